// Round 15
// baseline (1370.150 us; speedup 1.0000x reference)
//
#include <hip/hip_runtime.h>
#include <hip/hip_bf16.h>
#include <math.h>

#define N_USERS 2500
#define N_ITEMS 3000
#define N_ENT   2500
#define NTOT    8000
#define D       128
#define NEDGE   256000
#define NSLICE  8
#define NMAT    12

typedef unsigned short u16;
typedef unsigned int u32;
typedef unsigned long long u64;
typedef __attribute__((ext_vector_type(8))) short short8;
typedef __attribute__((ext_vector_type(4))) float f32x4;

static __device__ __forceinline__ u16 bf16bits(float x) {
  __hip_bfloat16 h = __float2bfloat16(x);
  return *reinterpret_cast<u16*>(&h);
}

// ---------------------------------------------------------------------------
// One-shot W pre-split of all 12 weight matrices into a u16 arena.
// ---------------------------------------------------------------------------
struct WsplitArgs {
  const float* w[NMAT];
  int useks[NMAT];
  int K[NMAT];
  int cum[NMAT + 1];
  int ofs[NMAT];
};

__global__ void k_wsplit_all(WsplitArgs a, const float* __restrict__ relmean,
                             u16* __restrict__ arena) {
  const int e = blockIdx.x * 256 + threadIdx.x;
  if (e >= a.cum[NMAT]) return;
  int i = 0;
  while (e >= a.cum[i + 1]) ++i;
  const int local = e - a.cum[i];
  const int k = local >> 7, j = local & 127;
  const int K = a.K[i];
  float x = a.w[i][(size_t)k * 128 + j];
  if (a.useks[i]) x *= relmean[k];
  const __hip_bfloat16 h1 = __float2bfloat16(x);
  const float r1 = x - __bfloat162float(h1);
  const __hip_bfloat16 h2 = __float2bfloat16(r1);
  const float r2 = r1 - __bfloat162float(h2);
  const __hip_bfloat16 h3 = __float2bfloat16(r2);
  u16* __restrict__ base = arena + a.ofs[i] + (size_t)j * K + k;
  base[0]               = *(const u16*)&h1;
  base[(size_t)128 * K] = *(const u16*)&h2;
  base[(size_t)256 * K] = *(const u16*)&h3;
}

// ---------------------------------------------------------------------------
// MFMA GEMM, f32-accurate via 3xbf16 splits (verified r11)
// ---------------------------------------------------------------------------
__global__ __launch_bounds__(256) void k_gemm3(const float* __restrict__ A,
                                               const u16* __restrict__ wsg,
                                               const float* __restrict__ b,
                                               float* __restrict__ out,
                                               u16* __restrict__ ob,
                                               int M, int K, int mode) {
  const int tid  = threadIdx.x;
  const int lane = tid & 63;
  const int wave = tid >> 6;
  const int rbase = blockIdx.x * 64 + wave * 16;
  const int colL = lane & 15;
  const int kofs = (lane >> 4) * 8;

  f32x4 acc[8];
#pragma unroll
  for (int ct = 0; ct < 8; ++ct) acc[ct] = (f32x4){0.f, 0.f, 0.f, 0.f};

  const int arow = (rbase + colL < M) ? (rbase + colL) : (M - 1);
  const float* __restrict__ arp = A + (size_t)arow * K;

  for (int k0 = 0; k0 < K; k0 += 32) {
    const float4 f0 = *(const float4*)(arp + k0 + kofs);
    const float4 f1 = *(const float4*)(arp + k0 + kofs + 4);
    float av[8] = {f0.x, f0.y, f0.z, f0.w, f1.x, f1.y, f1.z, f1.w};
    short8 a1, a2, a3;
#pragma unroll
    for (int e = 0; e < 8; ++e) {
      const float x = av[e];
      const __hip_bfloat16 h1 = __float2bfloat16(x);
      const float r1 = x - __bfloat162float(h1);
      const __hip_bfloat16 h2 = __float2bfloat16(r1);
      const float r2 = r1 - __bfloat162float(h2);
      const __hip_bfloat16 h3 = __float2bfloat16(r2);
      a1[e] = *(const short*)&h1;
      a2[e] = *(const short*)&h2;
      a3[e] = *(const short*)&h3;
    }
#pragma unroll
    for (int ct = 0; ct < 8; ++ct) {
      const int j = ct * 16 + colL;
      const u16* wp = wsg + (size_t)j * K + k0 + kofs;
      const short8 b1 = *(const short8*)wp;
      const short8 b2 = *(const short8*)(wp + (size_t)128 * K);
      const short8 b3 = *(const short8*)(wp + (size_t)256 * K);
      acc[ct] = __builtin_amdgcn_mfma_f32_16x16x32_bf16(a1, b1, acc[ct], 0, 0, 0);
      acc[ct] = __builtin_amdgcn_mfma_f32_16x16x32_bf16(a1, b2, acc[ct], 0, 0, 0);
      acc[ct] = __builtin_amdgcn_mfma_f32_16x16x32_bf16(a2, b1, acc[ct], 0, 0, 0);
      acc[ct] = __builtin_amdgcn_mfma_f32_16x16x32_bf16(a2, b2, acc[ct], 0, 0, 0);
      acc[ct] = __builtin_amdgcn_mfma_f32_16x16x32_bf16(a1, b3, acc[ct], 0, 0, 0);
      acc[ct] = __builtin_amdgcn_mfma_f32_16x16x32_bf16(a3, b1, acc[ct], 0, 0, 0);
    }
  }

#pragma unroll
  for (int ct = 0; ct < 8; ++ct) {
    const int j = ct * 16 + colL;
    const float bj = b[j];
#pragma unroll
    for (int r = 0; r < 4; ++r) {
      const int row = rbase + (lane >> 4) * 4 + r;
      if (row < M) {
        float c = acc[ct][r] + bj;
        if (mode == 1) c = fmaxf(c, 0.f);
        else if (mode == 2) c *= 2.f;
        out[(size_t)row * 128 + j] = c;
        if (ob) ob[(size_t)row * 128 + j] = bf16bits(c);
      }
    }
  }
}

// ---------------------------------------------------------------------------
// Dual-B MFMA GEMM (kn+vn share A) — verified r14
// ---------------------------------------------------------------------------
__global__ __launch_bounds__(256) void k_gemm3x2(const float* __restrict__ A,
                                                 const u16* __restrict__ wsgA,
                                                 const float* __restrict__ bA,
                                                 float* __restrict__ outA,
                                                 u16* __restrict__ obA,
                                                 const u16* __restrict__ wsgB,
                                                 const float* __restrict__ bB,
                                                 float* __restrict__ outB,
                                                 int M, int K) {
  const int tid  = threadIdx.x;
  const int lane = tid & 63;
  const int wave = tid >> 6;
  const int rbase = blockIdx.x * 64 + wave * 16;
  const int colL = lane & 15;
  const int kofs = (lane >> 4) * 8;

  f32x4 accA[8], accB[8];
#pragma unroll
  for (int ct = 0; ct < 8; ++ct) {
    accA[ct] = (f32x4){0.f, 0.f, 0.f, 0.f};
    accB[ct] = (f32x4){0.f, 0.f, 0.f, 0.f};
  }

  const int arow = (rbase + colL < M) ? (rbase + colL) : (M - 1);
  const float* __restrict__ arp = A + (size_t)arow * K;

  for (int k0 = 0; k0 < K; k0 += 32) {
    const float4 f0 = *(const float4*)(arp + k0 + kofs);
    const float4 f1 = *(const float4*)(arp + k0 + kofs + 4);
    float av[8] = {f0.x, f0.y, f0.z, f0.w, f1.x, f1.y, f1.z, f1.w};
    short8 a1, a2, a3;
#pragma unroll
    for (int e = 0; e < 8; ++e) {
      const float x = av[e];
      const __hip_bfloat16 h1 = __float2bfloat16(x);
      const float r1 = x - __bfloat162float(h1);
      const __hip_bfloat16 h2 = __float2bfloat16(r1);
      const float r2 = r1 - __bfloat162float(h2);
      const __hip_bfloat16 h3 = __float2bfloat16(r2);
      a1[e] = *(const short*)&h1;
      a2[e] = *(const short*)&h2;
      a3[e] = *(const short*)&h3;
    }
#pragma unroll
    for (int ct = 0; ct < 8; ++ct) {
      const int j = ct * 16 + colL;
      {
        const u16* wp = wsgA + (size_t)j * K + k0 + kofs;
        const short8 b1 = *(const short8*)wp;
        const short8 b2 = *(const short8*)(wp + (size_t)128 * K);
        const short8 b3 = *(const short8*)(wp + (size_t)256 * K);
        accA[ct] = __builtin_amdgcn_mfma_f32_16x16x32_bf16(a1, b1, accA[ct], 0, 0, 0);
        accA[ct] = __builtin_amdgcn_mfma_f32_16x16x32_bf16(a1, b2, accA[ct], 0, 0, 0);
        accA[ct] = __builtin_amdgcn_mfma_f32_16x16x32_bf16(a2, b1, accA[ct], 0, 0, 0);
        accA[ct] = __builtin_amdgcn_mfma_f32_16x16x32_bf16(a2, b2, accA[ct], 0, 0, 0);
        accA[ct] = __builtin_amdgcn_mfma_f32_16x16x32_bf16(a1, b3, accA[ct], 0, 0, 0);
        accA[ct] = __builtin_amdgcn_mfma_f32_16x16x32_bf16(a3, b1, accA[ct], 0, 0, 0);
      }
      {
        const u16* wp = wsgB + (size_t)j * K + k0 + kofs;
        const short8 b1 = *(const short8*)wp;
        const short8 b2 = *(const short8*)(wp + (size_t)128 * K);
        const short8 b3 = *(const short8*)(wp + (size_t)256 * K);
        accB[ct] = __builtin_amdgcn_mfma_f32_16x16x32_bf16(a1, b1, accB[ct], 0, 0, 0);
        accB[ct] = __builtin_amdgcn_mfma_f32_16x16x32_bf16(a1, b2, accB[ct], 0, 0, 0);
        accB[ct] = __builtin_amdgcn_mfma_f32_16x16x32_bf16(a2, b1, accB[ct], 0, 0, 0);
        accB[ct] = __builtin_amdgcn_mfma_f32_16x16x32_bf16(a2, b2, accB[ct], 0, 0, 0);
        accB[ct] = __builtin_amdgcn_mfma_f32_16x16x32_bf16(a1, b3, accB[ct], 0, 0, 0);
        accB[ct] = __builtin_amdgcn_mfma_f32_16x16x32_bf16(a3, b1, accB[ct], 0, 0, 0);
      }
    }
  }

#pragma unroll
  for (int ct = 0; ct < 8; ++ct) {
    const int j = ct * 16 + colL;
    const float bjA = bA[j];
    const float bjB = bB[j];
#pragma unroll
    for (int r = 0; r < 4; ++r) {
      const int row = rbase + (lane >> 4) * 4 + r;
      if (row < M) {
        const float cA = accA[ct][r] + bjA;
        outA[(size_t)row * 128 + j] = cA;
        obA[(size_t)row * 128 + j] = bf16bits(cA);
        outB[(size_t)row * 128 + j] = accB[ct][r] + bjB;
      }
    }
  }
}

// ---------------------------------------------------------------------------
// Gated fusion (unchanged)
// ---------------------------------------------------------------------------
__global__ void k_gatefuse(const float* __restrict__ base, const float* __restrict__ mm,
                           const float* __restrict__ gw, const float* __restrict__ gb,
                           float* __restrict__ embout) {
  const int r = blockIdx.x;
  const int j = threadIdx.x;
  const float* __restrict__ b0 = base + (size_t)r * D;
  const float* __restrict__ m0 = mm + (size_t)r * D;
  float acc = 0.f;
  for (int k = 0; k < D; ++k) acc = fmaf(b0[k], gw[(size_t)k * D + j], acc);
  for (int k = 0; k < D; ++k) acc = fmaf(m0[k], gw[(size_t)(D + k) * D + j], acc);
  acc += gb[j];
  const float s1 = 1.f / (1.f + expf(-acc));
  const float g  = 1.f / (1.f + expf(-(s1 * 2.f)));
  const float bv = b0[j], mv = m0[j];
  embout[(size_t)r * D + j] = g * bv + (1.f - g) * mv + 0.1f * bv;
}

__global__ void k_relmean(const float* __restrict__ rel, float* __restrict__ out) {
  const int j = threadIdx.x;
  float s = 0.f;
  for (int i = 0; i < 32; ++i) s += rel[i * D + j];
  out[j] = s * (1.f / 32.f);
}

__global__ void k_copy3(const float* __restrict__ ent, const float* __restrict__ item,
                        const float* __restrict__ mm, float* __restrict__ emb0ent,
                        float* __restrict__ outItem, float* __restrict__ outMM) {
  const int t = blockIdx.x * 256 + threadIdx.x;
  const int nEnt = N_ENT * D;
  const int nIt  = N_ITEMS * D;
  if (t < nEnt) emb0ent[t] = ent[t];
  if (t < nIt) {
    outItem[t] = item[t];
    outMM[t]   = mm[t];
  }
}

// ---------------------------------------------------------------------------
// CSR build (unchanged from r13)
// ---------------------------------------------------------------------------
__global__ void k_hist(const int* __restrict__ rw, int* __restrict__ cnt) {
  const int e = blockIdx.x * 256 + threadIdx.x;
  if (e < NEDGE) atomicAdd(&cnt[rw[e]], 1);
}

__global__ __launch_bounds__(1024) void k_scan(int* __restrict__ cnt,
                                               int* __restrict__ rowptr,
                                               int* __restrict__ cursor) {
  __shared__ int part[1024];
  const int t = threadIdx.x;
  const int base = t * 8;
  int loc[8];
  int s = 0;
#pragma unroll
  for (int j = 0; j < 8; ++j) {
    const int v = (base + j < NTOT) ? cnt[base + j] : 0;
    loc[j] = s; s += v;
  }
  part[t] = s;
  __syncthreads();
  for (int off = 1; off < 1024; off <<= 1) {
    const int v = (t >= off) ? part[t - off] : 0;
    __syncthreads();
    part[t] += v;
    __syncthreads();
  }
  const int pre = (t == 0) ? 0 : part[t - 1];
#pragma unroll
  for (int j = 0; j < 8; ++j) {
    if (base + j < NTOT) {
      const int p = pre + loc[j];
      rowptr[base + j] = p;
      cursor[base + j] = p;
    }
  }
  if (t == 1023) rowptr[NTOT] = part[1023];
}

__global__ void k_scatter(const int* __restrict__ rw, int* __restrict__ cursor,
                          int* __restrict__ perm) {
  const int e = blockIdx.x * 256 + threadIdx.x;
  if (e >= NEDGE) return;
  const int pos = atomicAdd(&cursor[rw[e]], 1);
  perm[pos] = e;
}

__global__ __launch_bounds__(128) void k_spmm_csr(const float* __restrict__ dat,
                                                  const int* __restrict__ cl,
                                                  const int* __restrict__ perm,
                                                  const int* __restrict__ rowptr,
                                                  const float* __restrict__ emb,
                                                  float* __restrict__ side) {
  const int r = blockIdx.x;
  const int d = threadIdx.x;
  const int beg = rowptr[r], end = rowptr[r + 1];
  float acc = 0.f;
  for (int i = beg; i < end; ++i) {
    const int ei = perm[i];
    acc = fmaf(dat[ei], emb[(size_t)cl[ei] * D + d], acc);
  }
  side[(size_t)r * D + d] = acc;
}

// ---------------------------------------------------------------------------
// bf16-MFMA score scan + shuffle-free top selection.
// r15 parity split of the proven r12 kernel for occupancy:
//  - 128-thr blocks, grid (500, 8); wave = tile PARITY within the slice
//    (even/odd tiles), 8000 waves total (2x r12).
//  - scan identical (cell-top-6, score-only bubble); cell streams ~31 >= 6.
//  - merge stage 1: each parity ranks its own 96 keys (verbatim r12 loop,
//    4 phases of 8 rows) -> own-parity top-16 into k2[p][row][rank] (exactly
//    16 slots, always filled: 96 unique keys).
//  - merge stage 2: union rank = own rank q + #greater among OTHER parity's
//    top-16. Exact whenever union rank < 16 (a better key outside the other
//    top-16 implies >=16 better keys that also beat us -> consistently
//    excluded). cand gets exactly the slice-top-16, bijective slots.
// Downstream semantics identical to r12; rescore unchanged.
// ---------------------------------------------------------------------------
__global__ __launch_bounds__(128) void k_topk6p(const u16* __restrict__ qb,
                                                const u16* __restrict__ kb,
                                                int* __restrict__ cand) {
  __shared__ u64 km[8][97];
  __shared__ u64 k2[2][16][17];
  __shared__ int c2[2][16][17];
  const int tid  = threadIdx.x;
  const int lane = tid & 63;
  const int wave = tid >> 6;        // parity
  const int rbase = blockIdx.x * 16;
  const int sl   = blockIdx.y;
  const int colL = lane & 15;
  const int g    = lane >> 4;
  const int kofs = g * 8;

  short8 aF[4];
  {
    const u16* ap = qb + (size_t)(rbase + colL) * D + kofs;
#pragma unroll
    for (int t = 0; t < 4; ++t) aF[t] = *reinterpret_cast<const short8*>(ap + t * 32);
  }

  float s[4][6]; int c[4][6];
#pragma unroll
  for (int r = 0; r < 4; ++r)
#pragma unroll
    for (int j = 0; j < 6; ++j) { s[r][j] = -3.0e38f; c[r][j] = 0x40000000 + colL * 6 + j; }

  const int tile0  = sl * 62 + (sl < 4 ? sl : 4);
  const int ntiles = 62 + (sl < 4 ? 1 : 0);
  const u16* bb = kb + (size_t)(tile0 * 16 + colL) * D + kofs;

  int ct = wave;
  short8 bF[4];
#pragma unroll
  for (int t = 0; t < 4; ++t)
    bF[t] = *reinterpret_cast<const short8*>(bb + (size_t)ct * 16 * D + t * 32);

  for (; ct < ntiles; ct += 2) {
    const int cn = (ct + 2 < ntiles) ? ct + 2 : ct;
    const u16* nb = bb + (size_t)cn * 16 * D;
    short8 bN[4];
#pragma unroll
    for (int t = 0; t < 4; ++t) bN[t] = *reinterpret_cast<const short8*>(nb + t * 32);

    f32x4 acc = {0.f, 0.f, 0.f, 0.f};
#pragma unroll
    for (int t = 0; t < 4; ++t)
      acc = __builtin_amdgcn_mfma_f32_16x16x32_bf16(aF[t], bF[t], acc, 0, 0, 0);

    const int colIdx = (tile0 + ct) * 16 + colL;
#pragma unroll
    for (int r = 0; r < 4; ++r) {
      float ks = acc[r]; int kc = colIdx;
      if (ks > s[r][5]) {
#pragma unroll
        for (int i = 0; i < 6; ++i) {
          const bool bgt = ks > s[r][i];
          const float os = s[r][i]; const int oc = c[r][i];
          s[r][i] = bgt ? ks : os;  c[r][i] = bgt ? kc : oc;
          ks      = bgt ? os : ks;  kc      = bgt ? oc : kc;
        }
      }
    }

#pragma unroll
    for (int t = 0; t < 4; ++t) bF[t] = bN[t];
  }

  // pack survivors to exact u64 keys (score desc, col asc order)
  u64 kk[4][6];
#pragma unroll
  for (int r = 0; r < 4; ++r)
#pragma unroll
    for (int j = 0; j < 6; ++j) {
      const u32 b = __builtin_bit_cast(u32, s[r][j]);
      const u32 mono = b ^ ((u32)(((int)b) >> 31) | 0x80000000u);
      kk[r][j] = ((u64)mono << 32) | (u64)(0xFFFFFFFFu - (u32)c[r][j]);
    }

  // ---- stage 1: own-parity rank (4 phases: parity x row-half) ----
  for (int p = 0; p < 2; ++p) {
    for (int h = 0; h < 2; ++h) {
      const bool act = (wave == p) && ((g >> 1) == h);
      if (act) {
#pragma unroll
        for (int r = 0; r < 4; ++r)
#pragma unroll
          for (int j = 0; j < 6; ++j)
            km[4 * (g & 1) + r][colL * 6 + j] = kk[r][j];
      }
      __syncthreads();
      if (act) {
#pragma unroll
        for (int r = 0; r < 4; ++r) {
          const int row8 = 4 * (g & 1) + r;
          int cnt[6] = {0, 0, 0, 0, 0, 0};
#pragma unroll 8
          for (int q2 = 0; q2 < 96; ++q2) {
            const u64 o = km[row8][q2];
#pragma unroll
            for (int j = 0; j < 6; ++j) cnt[j] += (o > kk[r][j]) ? 1 : 0;
          }
          const int row = 4 * g + r;     // 0..15 within row-group
#pragma unroll
          for (int j = 0; j < 6; ++j)
            if (cnt[j] < 16) {
              k2[p][row][cnt[j]] = kk[r][j];
              c2[p][row][cnt[j]] = c[r][j];
            }
        }
      }
      __syncthreads();
    }
  }

  // ---- stage 2: cross-parity union rank; wave handles own parity ----
  {
    const int row = lane >> 2;
    const int q0 = (lane & 3) * 4;
#pragma unroll
    for (int qq = 0; qq < 4; ++qq) {
      const int q = q0 + qq;
      const u64 key = k2[wave][row][q];
      int cnt1 = 0;
#pragma unroll
      for (int q2 = 0; q2 < 16; ++q2)
        cnt1 += (k2[1 - wave][row][q2] > key) ? 1 : 0;
      const int slot = q + cnt1;
      if (slot < 16)
        cand[(size_t)(rbase + row) * 128 + sl * 16 + slot] = c2[wave][row][q];
    }
  }
}

// ---------------------------------------------------------------------------
// Exact f32 rescore of 128 candidates (unchanged)
// ---------------------------------------------------------------------------
__global__ __launch_bounds__(64) void k_rescore128(const float* __restrict__ qn,
                                                   const float* __restrict__ kn,
                                                   const float* __restrict__ vn,
                                                   const int* __restrict__ cand,
                                                   float* __restrict__ enext) {
  const int row = blockIdx.x;
  const int lane = threadIdx.x;
  const int* cr = cand + (size_t)row * 128;
  const int c0 = cr[lane];
  const int c1 = cr[64 + lane];

  const float4* __restrict__ q4  = (const float4*)(qn + (size_t)row * D);
  const float4* __restrict__ k40 = (const float4*)(kn + (size_t)c0 * D);
  const float4* __restrict__ k41 = (const float4*)(kn + (size_t)c1 * D);
  float s0 = 0.f, s1 = 0.f;
#pragma unroll 8
  for (int j = 0; j < 32; ++j) {
    const float4 qv = q4[j];
    const float4 a = k40[j], b = k41[j];
    s0 = fmaf(qv.x, a.x, s0); s0 = fmaf(qv.y, a.y, s0);
    s0 = fmaf(qv.z, a.z, s0); s0 = fmaf(qv.w, a.w, s0);
    s1 = fmaf(qv.x, b.x, s1); s1 = fmaf(qv.y, b.y, s1);
    s1 = fmaf(qv.z, b.z, s1); s1 = fmaf(qv.w, b.w, s1);
  }
  const float inv = 0.088388347648318447f;   // 1/sqrt(128)
  s0 *= inv; s1 *= inv;

  int r0 = 0, r1 = 0;
  for (int j = 0; j < 64; ++j) {
    const float t0 = __shfl(s0, j), t1 = __shfl(s1, j);
    const int   u0 = __shfl(c0, j), u1 = __shfl(c1, j);
    r0 += (t0 > s0 || (t0 == s0 && u0 < c0)) ? 1 : 0;
    r0 += (t1 > s0 || (t1 == s0 && u1 < c0)) ? 1 : 0;
    r1 += (t0 > s1 || (t0 == s1 && u0 < c1)) ? 1 : 0;
    r1 += (t1 > s1 || (t1 == s1 && u1 < c1)) ? 1 : 0;
  }
  const bool sel0 = r0 < 16, sel1 = r1 < 16;

  float v = fmaxf(sel0 ? s0 : -3.0e38f, sel1 ? s1 : -3.0e38f);
#pragma unroll
  for (int d2 = 1; d2 < 64; d2 <<= 1) v = fmaxf(v, __shfl_xor(v, d2));
  const float e0 = sel0 ? expf(s0 - v) : 0.f;
  const float e1 = sel1 ? expf(s1 - v) : 0.f;
  float Z = e0 + e1;
#pragma unroll
  for (int d2 = 1; d2 < 64; d2 <<= 1) Z += __shfl_xor(Z, d2);
  const float w0 = e0 / Z, w1 = e1 / Z;

  float a0 = 0.f, a1 = 0.f;
  unsigned long long b0 = __ballot(sel0);
  while (b0) {
    const int src = __ffsll(b0) - 1; b0 &= b0 - 1;
    const float wj = __shfl(w0, src);
    const int   cj = __shfl(c0, src);
    const float* __restrict__ vr = vn + (size_t)cj * D;
    a0 = fmaf(wj, vr[lane], a0);
    a1 = fmaf(wj, vr[64 + lane], a1);
  }
  unsigned long long b1 = __ballot(sel1);
  while (b1) {
    const int src = __ffsll(b1) - 1; b1 &= b1 - 1;
    const float wj = __shfl(w1, src);
    const int   cj = __shfl(c1, src);
    const float* __restrict__ vr = vn + (size_t)cj * D;
    a0 = fmaf(wj, vr[lane], a0);
    a1 = fmaf(wj, vr[64 + lane], a1);
  }
  enext[(size_t)row * D + lane]      = fmaxf(a0, 0.f);
  enext[(size_t)row * D + 64 + lane] = fmaxf(a1, 0.f);
}

// ---------------------------------------------------------------------------
// final = [e0|e1|e2] @ la_w + la_b, row-L2-normalized (unchanged)
// ---------------------------------------------------------------------------
__global__ void k_final_norm(const float* __restrict__ e0, const float* __restrict__ e1,
                             const float* __restrict__ e2, const float* __restrict__ law,
                             const float* __restrict__ lab, float* __restrict__ out) {
  __shared__ float red[128];
  const int r = blockIdx.x;
  const int j = threadIdx.x;
  const float* __restrict__ a0 = e0 + (size_t)r * D;
  const float* __restrict__ a1 = e1 + (size_t)r * D;
  const float* __restrict__ a2 = e2 + (size_t)r * D;
  float acc = lab[j];
  for (int k = 0; k < D; ++k) acc = fmaf(a0[k], law[(size_t)k * D + j], acc);
  for (int k = 0; k < D; ++k) acc = fmaf(a1[k], law[(size_t)(D + k) * D + j], acc);
  for (int k = 0; k < D; ++k) acc = fmaf(a2[k], law[(size_t)(2 * D + k) * D + j], acc);
  red[j] = acc * acc;
  __syncthreads();
  for (int st = 64; st > 0; st >>= 1) {
    if (j < st) red[j] += red[j + st];
    __syncthreads();
  }
  const float nrm = fmaxf(sqrtf(red[0]), 1e-12f);
  const float o = acc / nrm;
  if (r < N_USERS) out[(size_t)r * D + j] = o;
  else             out[(size_t)N_USERS * D + (size_t)(r - N_USERS) * D + j] = o;
}

// ---------------------------------------------------------------------------
extern "C" void kernel_launch(void* const* d_in, const int* in_sizes, int n_in,
                              void* d_out, int out_size, void* d_ws, size_t ws_size,
                              hipStream_t stream) {
  const float* user_w = (const float*)d_in[0];
  const float* item_w = (const float*)d_in[1];
  const float* ent_w  = (const float*)d_in[2];
  const float* rel_w  = (const float*)d_in[3];
  const float* mfeat  = (const float*)d_in[4];
  const float* ufeat  = (const float*)d_in[5];
  const float* me_w1  = (const float*)d_in[6];
  const float* me_b1  = (const float*)d_in[7];
  const float* me_w2  = (const float*)d_in[8];
  const float* me_b2  = (const float*)d_in[9];
  const float* ue_w1  = (const float*)d_in[10];
  const float* ue_b1  = (const float*)d_in[11];
  const float* ue_w2  = (const float*)d_in[12];
  const float* ue_b2  = (const float*)d_in[13];
  const float* cm_vw  = (const float*)d_in[18];
  const float* cm_vb  = (const float*)d_in[19];
  const float* cm_ow  = (const float*)d_in[20];
  const float* cm_ob  = (const float*)d_in[21];
  const float* mg_w   = (const float*)d_in[22];
  const float* mg_b   = (const float*)d_in[23];
  const float* ug_w   = (const float*)d_in[24];
  const float* ug_b   = (const float*)d_in[25];
  const float* gnn_qw = (const float*)d_in[26];
  const float* gnn_qb = (const float*)d_in[27];
  const float* gnn_kw = (const float*)d_in[28];
  const float* gnn_kb = (const float*)d_in[29];
  const float* gnn_vw = (const float*)d_in[30];
  const float* gnn_vb = (const float*)d_in[31];
  const float* la_w   = (const float*)d_in[32];
  const float* la_b   = (const float*)d_in[33];
  const float* adj_d  = (const float*)d_in[34];
  const int*   adj_r  = (const int*)d_in[35];
  const int*   adj_c  = (const int*)d_in[36];
  float* out = (float*)d_out;
  float* ws  = (float*)d_ws;

  // ---- workspace layout (floats) ----
  size_t off = 0;
  float* mm_item = ws + off; off += (size_t)N_ITEMS * D;
  float* mm_user = ws + off; off += (size_t)N_USERS * D;
  float* enc     = ws + off; off += (size_t)N_ITEMS * D;
  float* tmp     = ws + off; off += (size_t)N_ITEMS * D;
  float* emb0    = ws + off; off += (size_t)NTOT * D;
  float* emb1    = ws + off; off += (size_t)NTOT * D;
  float* emb2    = ws + off; off += (size_t)NTOT * D;
  float* side    = ws + off; off += (size_t)NTOT * D;
  float* qn      = ws + off; off += (size_t)NTOT * D;
  float* kn      = ws + off; off += (size_t)NTOT * D;
  float* vn      = ws + off; off += (size_t)NTOT * D;
  float* relmean = ws + off; off += D;
  u16* arena = (u16*)(ws + off); off += 491520;
  u16* qb = (u16*)mm_user;
  u16* kb = qb + (size_t)NTOT * D;
  int* cand = (int*)side;
  int* rowptr = (int*)emb2;
  int* cursor = rowptr + 8064;
  int* permB  = cursor + 8064;

  // order: me_w1, me_w2, ue_w1, ue_w2, cm_vw, cm_ow, qw0, kw0, vw0, qw1, kw1, vw1
  static const int Ks[NMAT]  = {768, 128, 512, 128, 128, 128, 128, 128, 128, 128, 128, 128};
  int ofs[NMAT], cum[NMAT + 1];
  {
    int o = 0, cc = 0;
    for (int i = 0; i < NMAT; ++i) {
      ofs[i] = o; o += 3 * Ks[i] * 128;
      cum[i] = cc; cc += Ks[i] * 128;
    }
    cum[NMAT] = cc;
  }

  WsplitArgs wa;
  const float* wptr[NMAT] = {me_w1, me_w2, ue_w1, ue_w2, cm_vw, cm_ow,
                             gnn_qw, gnn_kw, gnn_vw,
                             gnn_qw + (size_t)D * D, gnn_kw + (size_t)D * D,
                             gnn_vw + (size_t)D * D};
  for (int i = 0; i < NMAT; ++i) {
    wa.w[i] = wptr[i];
    wa.useks[i] = (i == 7 || i == 10) ? 1 : 0;
    wa.K[i] = Ks[i];
    wa.cum[i] = cum[i];
    wa.ofs[i] = ofs[i];
  }
  wa.cum[NMAT] = cum[NMAT];

  k_relmean<<<1, D, 0, stream>>>(rel_w, relmean);
  k_wsplit_all<<<(cum[NMAT] + 255) / 256, 256, 0, stream>>>(wa, relmean, arena);

  // ---- modality encoders ----
  k_gemm3<<<(3000 + 63) / 64, 256, 0, stream>>>(mfeat, arena + ofs[0], me_b1, tmp, nullptr, 3000, 768, 1);
  k_gemm3<<<(3000 + 63) / 64, 256, 0, stream>>>(tmp, arena + ofs[1], me_b2, enc, nullptr, 3000, 128, 1);
  k_gemm3<<<(2500 + 63) / 64, 256, 0, stream>>>(ufeat, arena + ofs[2], ue_b1, tmp, nullptr, 2500, 512, 1);
  k_gemm3<<<(2500 + 63) / 64, 256, 0, stream>>>(tmp, arena + ofs[3], ue_b2, mm_user, nullptr, 2500, 128, 1);
  k_gemm3<<<(3000 + 63) / 64, 256, 0, stream>>>(enc, arena + ofs[4], cm_vb, tmp, nullptr, 3000, 128, 0);
  k_gemm3<<<(3000 + 63) / 64, 256, 0, stream>>>(tmp, arena + ofs[5], cm_ob, mm_item, nullptr, 3000, 128, 2);
  // ---- gated fusion -> emb0; copies fused ----
  k_gatefuse<<<N_ITEMS, D, 0, stream>>>(item_w, mm_item, mg_w, mg_b, emb0 + (size_t)N_USERS * D);
  k_gatefuse<<<N_USERS, D, 0, stream>>>(user_w, mm_user, ug_w, ug_b, emb0);
  k_copy3<<<(N_ITEMS * D + 255) / 256, 256, 0, stream>>>(
      ent_w, item_w, mm_item,
      emb0 + (size_t)(N_USERS + N_ITEMS) * D,
      out + (size_t)(N_USERS + N_ITEMS) * D,
      out + (size_t)(N_USERS + 2 * N_ITEMS) * D);

  // ---- CSR build ----
  hipMemsetAsync(cursor, 0, NTOT * sizeof(int), stream);
  k_hist<<<(NEDGE + 255) / 256, 256, 0, stream>>>(adj_r, cursor);
  k_scan<<<1, 1024, 0, stream>>>(cursor, rowptr, cursor);
  k_scatter<<<(NEDGE + 255) / 256, 256, 0, stream>>>(adj_r, cursor, permB);

  // ---- GNN layers ----
  const float* eml[3] = {emb0, emb1, emb2};
  for (int l = 0; l < 2; ++l) {
    const float* e = eml[l];
    float* enext   = (float*)eml[l + 1];
    k_spmm_csr<<<NTOT, 128, 0, stream>>>(adj_d, adj_c, permB, rowptr, e, side);
    k_gemm3<<<(NTOT + 63) / 64, 256, 0, stream>>>(e, arena + ofs[6 + 3 * l],
                                                  gnn_qb + (size_t)l * D, qn, qb, NTOT, 128, 0);
    k_gemm3x2<<<(NTOT + 63) / 64, 256, 0, stream>>>(side,
                                                    arena + ofs[7 + 3 * l], gnn_kb + (size_t)l * D, kn, kb,
                                                    arena + ofs[8 + 3 * l], gnn_vb + (size_t)l * D, vn,
                                                    NTOT, 128);
    dim3 tkgrid(NTOT / 16, NSLICE);
    k_topk6p<<<tkgrid, 128, 0, stream>>>(qb, kb, cand);
    k_rescore128<<<NTOT, 64, 0, stream>>>(qn, kn, vn, cand, enext);
  }

  // ---- layer aggregation + normalize -> d_out ----
  k_final_norm<<<N_USERS + N_ITEMS, D, 0, stream>>>(emb0, emb1, emb2, la_w, la_b, out);
}

// Round 16
// 1145.812 us; speedup vs baseline: 1.1958x; 1.1958x over previous
//
#include <hip/hip_runtime.h>
#include <hip/hip_bf16.h>
#include <math.h>

#define N_USERS 2500
#define N_ITEMS 3000
#define N_ENT   2500
#define NTOT    8000
#define D       128
#define NEDGE   256000
#define NSLICE  8
#define NMAT    12

typedef unsigned short u16;
typedef unsigned int u32;
typedef unsigned long long u64;
typedef __attribute__((ext_vector_type(8))) short short8;
typedef __attribute__((ext_vector_type(4))) float f32x4;

static __device__ __forceinline__ u16 bf16bits(float x) {
  __hip_bfloat16 h = __float2bfloat16(x);
  return *reinterpret_cast<u16*>(&h);
}

// ---------------------------------------------------------------------------
// One-shot W pre-split of all 12 weight matrices into a u16 arena.
// ---------------------------------------------------------------------------
struct WsplitArgs {
  const float* w[NMAT];
  int useks[NMAT];
  int K[NMAT];
  int cum[NMAT + 1];
  int ofs[NMAT];
};

__global__ void k_wsplit_all(WsplitArgs a, const float* __restrict__ relmean,
                             u16* __restrict__ arena) {
  const int e = blockIdx.x * 256 + threadIdx.x;
  if (e >= a.cum[NMAT]) return;
  int i = 0;
  while (e >= a.cum[i + 1]) ++i;
  const int local = e - a.cum[i];
  const int k = local >> 7, j = local & 127;
  const int K = a.K[i];
  float x = a.w[i][(size_t)k * 128 + j];
  if (a.useks[i]) x *= relmean[k];
  const __hip_bfloat16 h1 = __float2bfloat16(x);
  const float r1 = x - __bfloat162float(h1);
  const __hip_bfloat16 h2 = __float2bfloat16(r1);
  const float r2 = r1 - __bfloat162float(h2);
  const __hip_bfloat16 h3 = __float2bfloat16(r2);
  u16* __restrict__ base = arena + a.ofs[i] + (size_t)j * K + k;
  base[0]               = *(const u16*)&h1;
  base[(size_t)128 * K] = *(const u16*)&h2;
  base[(size_t)256 * K] = *(const u16*)&h3;
}

// ---------------------------------------------------------------------------
// MFMA GEMM, f32-accurate via 3xbf16 splits (verified r11)
// ---------------------------------------------------------------------------
__global__ __launch_bounds__(256) void k_gemm3(const float* __restrict__ A,
                                               const u16* __restrict__ wsg,
                                               const float* __restrict__ b,
                                               float* __restrict__ out,
                                               u16* __restrict__ ob,
                                               int M, int K, int mode) {
  const int tid  = threadIdx.x;
  const int lane = tid & 63;
  const int wave = tid >> 6;
  const int rbase = blockIdx.x * 64 + wave * 16;
  const int colL = lane & 15;
  const int kofs = (lane >> 4) * 8;

  f32x4 acc[8];
#pragma unroll
  for (int ct = 0; ct < 8; ++ct) acc[ct] = (f32x4){0.f, 0.f, 0.f, 0.f};

  const int arow = (rbase + colL < M) ? (rbase + colL) : (M - 1);
  const float* __restrict__ arp = A + (size_t)arow * K;

  for (int k0 = 0; k0 < K; k0 += 32) {
    const float4 f0 = *(const float4*)(arp + k0 + kofs);
    const float4 f1 = *(const float4*)(arp + k0 + kofs + 4);
    float av[8] = {f0.x, f0.y, f0.z, f0.w, f1.x, f1.y, f1.z, f1.w};
    short8 a1, a2, a3;
#pragma unroll
    for (int e = 0; e < 8; ++e) {
      const float x = av[e];
      const __hip_bfloat16 h1 = __float2bfloat16(x);
      const float r1 = x - __bfloat162float(h1);
      const __hip_bfloat16 h2 = __float2bfloat16(r1);
      const float r2 = r1 - __bfloat162float(h2);
      const __hip_bfloat16 h3 = __float2bfloat16(r2);
      a1[e] = *(const short*)&h1;
      a2[e] = *(const short*)&h2;
      a3[e] = *(const short*)&h3;
    }
#pragma unroll
    for (int ct = 0; ct < 8; ++ct) {
      const int j = ct * 16 + colL;
      const u16* wp = wsg + (size_t)j * K + k0 + kofs;
      const short8 b1 = *(const short8*)wp;
      const short8 b2 = *(const short8*)(wp + (size_t)128 * K);
      const short8 b3 = *(const short8*)(wp + (size_t)256 * K);
      acc[ct] = __builtin_amdgcn_mfma_f32_16x16x32_bf16(a1, b1, acc[ct], 0, 0, 0);
      acc[ct] = __builtin_amdgcn_mfma_f32_16x16x32_bf16(a1, b2, acc[ct], 0, 0, 0);
      acc[ct] = __builtin_amdgcn_mfma_f32_16x16x32_bf16(a2, b1, acc[ct], 0, 0, 0);
      acc[ct] = __builtin_amdgcn_mfma_f32_16x16x32_bf16(a2, b2, acc[ct], 0, 0, 0);
      acc[ct] = __builtin_amdgcn_mfma_f32_16x16x32_bf16(a1, b3, acc[ct], 0, 0, 0);
      acc[ct] = __builtin_amdgcn_mfma_f32_16x16x32_bf16(a3, b1, acc[ct], 0, 0, 0);
    }
  }

#pragma unroll
  for (int ct = 0; ct < 8; ++ct) {
    const int j = ct * 16 + colL;
    const float bj = b[j];
#pragma unroll
    for (int r = 0; r < 4; ++r) {
      const int row = rbase + (lane >> 4) * 4 + r;
      if (row < M) {
        float c = acc[ct][r] + bj;
        if (mode == 1) c = fmaxf(c, 0.f);
        else if (mode == 2) c *= 2.f;
        out[(size_t)row * 128 + j] = c;
        if (ob) ob[(size_t)row * 128 + j] = bf16bits(c);
      }
    }
  }
}

// ---------------------------------------------------------------------------
// Dual-B MFMA GEMM (kn+vn share A) — verified r14
// ---------------------------------------------------------------------------
__global__ __launch_bounds__(256) void k_gemm3x2(const float* __restrict__ A,
                                                 const u16* __restrict__ wsgA,
                                                 const float* __restrict__ bA,
                                                 float* __restrict__ outA,
                                                 u16* __restrict__ obA,
                                                 const u16* __restrict__ wsgB,
                                                 const float* __restrict__ bB,
                                                 float* __restrict__ outB,
                                                 int M, int K) {
  const int tid  = threadIdx.x;
  const int lane = tid & 63;
  const int wave = tid >> 6;
  const int rbase = blockIdx.x * 64 + wave * 16;
  const int colL = lane & 15;
  const int kofs = (lane >> 4) * 8;

  f32x4 accA[8], accB[8];
#pragma unroll
  for (int ct = 0; ct < 8; ++ct) {
    accA[ct] = (f32x4){0.f, 0.f, 0.f, 0.f};
    accB[ct] = (f32x4){0.f, 0.f, 0.f, 0.f};
  }

  const int arow = (rbase + colL < M) ? (rbase + colL) : (M - 1);
  const float* __restrict__ arp = A + (size_t)arow * K;

  for (int k0 = 0; k0 < K; k0 += 32) {
    const float4 f0 = *(const float4*)(arp + k0 + kofs);
    const float4 f1 = *(const float4*)(arp + k0 + kofs + 4);
    float av[8] = {f0.x, f0.y, f0.z, f0.w, f1.x, f1.y, f1.z, f1.w};
    short8 a1, a2, a3;
#pragma unroll
    for (int e = 0; e < 8; ++e) {
      const float x = av[e];
      const __hip_bfloat16 h1 = __float2bfloat16(x);
      const float r1 = x - __bfloat162float(h1);
      const __hip_bfloat16 h2 = __float2bfloat16(r1);
      const float r2 = r1 - __bfloat162float(h2);
      const __hip_bfloat16 h3 = __float2bfloat16(r2);
      a1[e] = *(const short*)&h1;
      a2[e] = *(const short*)&h2;
      a3[e] = *(const short*)&h3;
    }
#pragma unroll
    for (int ct = 0; ct < 8; ++ct) {
      const int j = ct * 16 + colL;
      {
        const u16* wp = wsgA + (size_t)j * K + k0 + kofs;
        const short8 b1 = *(const short8*)wp;
        const short8 b2 = *(const short8*)(wp + (size_t)128 * K);
        const short8 b3 = *(const short8*)(wp + (size_t)256 * K);
        accA[ct] = __builtin_amdgcn_mfma_f32_16x16x32_bf16(a1, b1, accA[ct], 0, 0, 0);
        accA[ct] = __builtin_amdgcn_mfma_f32_16x16x32_bf16(a1, b2, accA[ct], 0, 0, 0);
        accA[ct] = __builtin_amdgcn_mfma_f32_16x16x32_bf16(a2, b1, accA[ct], 0, 0, 0);
        accA[ct] = __builtin_amdgcn_mfma_f32_16x16x32_bf16(a2, b2, accA[ct], 0, 0, 0);
        accA[ct] = __builtin_amdgcn_mfma_f32_16x16x32_bf16(a1, b3, accA[ct], 0, 0, 0);
        accA[ct] = __builtin_amdgcn_mfma_f32_16x16x32_bf16(a3, b1, accA[ct], 0, 0, 0);
      }
      {
        const u16* wp = wsgB + (size_t)j * K + k0 + kofs;
        const short8 b1 = *(const short8*)wp;
        const short8 b2 = *(const short8*)(wp + (size_t)128 * K);
        const short8 b3 = *(const short8*)(wp + (size_t)256 * K);
        accB[ct] = __builtin_amdgcn_mfma_f32_16x16x32_bf16(a1, b1, accB[ct], 0, 0, 0);
        accB[ct] = __builtin_amdgcn_mfma_f32_16x16x32_bf16(a1, b2, accB[ct], 0, 0, 0);
        accB[ct] = __builtin_amdgcn_mfma_f32_16x16x32_bf16(a2, b1, accB[ct], 0, 0, 0);
        accB[ct] = __builtin_amdgcn_mfma_f32_16x16x32_bf16(a2, b2, accB[ct], 0, 0, 0);
        accB[ct] = __builtin_amdgcn_mfma_f32_16x16x32_bf16(a1, b3, accB[ct], 0, 0, 0);
        accB[ct] = __builtin_amdgcn_mfma_f32_16x16x32_bf16(a3, b1, accB[ct], 0, 0, 0);
      }
    }
  }

#pragma unroll
  for (int ct = 0; ct < 8; ++ct) {
    const int j = ct * 16 + colL;
    const float bjA = bA[j];
    const float bjB = bB[j];
#pragma unroll
    for (int r = 0; r < 4; ++r) {
      const int row = rbase + (lane >> 4) * 4 + r;
      if (row < M) {
        const float cA = accA[ct][r] + bjA;
        outA[(size_t)row * 128 + j] = cA;
        obA[(size_t)row * 128 + j] = bf16bits(cA);
        outB[(size_t)row * 128 + j] = accB[ct][r] + bjB;
      }
    }
  }
}

// ---------------------------------------------------------------------------
// Gated fusion (unchanged)
// ---------------------------------------------------------------------------
__global__ void k_gatefuse(const float* __restrict__ base, const float* __restrict__ mm,
                           const float* __restrict__ gw, const float* __restrict__ gb,
                           float* __restrict__ embout) {
  const int r = blockIdx.x;
  const int j = threadIdx.x;
  const float* __restrict__ b0 = base + (size_t)r * D;
  const float* __restrict__ m0 = mm + (size_t)r * D;
  float acc = 0.f;
  for (int k = 0; k < D; ++k) acc = fmaf(b0[k], gw[(size_t)k * D + j], acc);
  for (int k = 0; k < D; ++k) acc = fmaf(m0[k], gw[(size_t)(D + k) * D + j], acc);
  acc += gb[j];
  const float s1 = 1.f / (1.f + expf(-acc));
  const float g  = 1.f / (1.f + expf(-(s1 * 2.f)));
  const float bv = b0[j], mv = m0[j];
  embout[(size_t)r * D + j] = g * bv + (1.f - g) * mv + 0.1f * bv;
}

__global__ void k_relmean(const float* __restrict__ rel, float* __restrict__ out) {
  const int j = threadIdx.x;
  float s = 0.f;
  for (int i = 0; i < 32; ++i) s += rel[i * D + j];
  out[j] = s * (1.f / 32.f);
}

__global__ void k_copy3(const float* __restrict__ ent, const float* __restrict__ item,
                        const float* __restrict__ mm, float* __restrict__ emb0ent,
                        float* __restrict__ outItem, float* __restrict__ outMM) {
  const int t = blockIdx.x * 256 + threadIdx.x;
  const int nEnt = N_ENT * D;
  const int nIt  = N_ITEMS * D;
  if (t < nEnt) emb0ent[t] = ent[t];
  if (t < nIt) {
    outItem[t] = item[t];
    outMM[t]   = mm[t];
  }
}

// ---------------------------------------------------------------------------
// CSR build (unchanged from r13)
// ---------------------------------------------------------------------------
__global__ void k_hist(const int* __restrict__ rw, int* __restrict__ cnt) {
  const int e = blockIdx.x * 256 + threadIdx.x;
  if (e < NEDGE) atomicAdd(&cnt[rw[e]], 1);
}

__global__ __launch_bounds__(1024) void k_scan(int* __restrict__ cnt,
                                               int* __restrict__ rowptr,
                                               int* __restrict__ cursor) {
  __shared__ int part[1024];
  const int t = threadIdx.x;
  const int base = t * 8;
  int loc[8];
  int s = 0;
#pragma unroll
  for (int j = 0; j < 8; ++j) {
    const int v = (base + j < NTOT) ? cnt[base + j] : 0;
    loc[j] = s; s += v;
  }
  part[t] = s;
  __syncthreads();
  for (int off = 1; off < 1024; off <<= 1) {
    const int v = (t >= off) ? part[t - off] : 0;
    __syncthreads();
    part[t] += v;
    __syncthreads();
  }
  const int pre = (t == 0) ? 0 : part[t - 1];
#pragma unroll
  for (int j = 0; j < 8; ++j) {
    if (base + j < NTOT) {
      const int p = pre + loc[j];
      rowptr[base + j] = p;
      cursor[base + j] = p;
    }
  }
  if (t == 1023) rowptr[NTOT] = part[1023];
}

__global__ void k_scatter(const int* __restrict__ rw, int* __restrict__ cursor,
                          int* __restrict__ perm) {
  const int e = blockIdx.x * 256 + threadIdx.x;
  if (e >= NEDGE) return;
  const int pos = atomicAdd(&cursor[rw[e]], 1);
  perm[pos] = e;
}

__global__ __launch_bounds__(128) void k_spmm_csr(const float* __restrict__ dat,
                                                  const int* __restrict__ cl,
                                                  const int* __restrict__ perm,
                                                  const int* __restrict__ rowptr,
                                                  const float* __restrict__ emb,
                                                  float* __restrict__ side) {
  const int r = blockIdx.x;
  const int d = threadIdx.x;
  const int beg = rowptr[r], end = rowptr[r + 1];
  float acc = 0.f;
  for (int i = beg; i < end; ++i) {
    const int ei = perm[i];
    acc = fmaf(dat[ei], emb[(size_t)cl[ei] * D + d], acc);
  }
  side[(size_t)r * D + d] = acc;
}

// ---------------------------------------------------------------------------
// bf16-MFMA score scan + shuffle-free top selection (r12 version, PROVEN:
// 202 us each at 4 waves/block, grid (500,2))
// ---------------------------------------------------------------------------
__global__ __launch_bounds__(256) void k_topk6v(const u16* __restrict__ qb,
                                                const u16* __restrict__ kb,
                                                int* __restrict__ cand) {
  __shared__ u64 km[4][8][97];
  const int tid  = threadIdx.x;
  const int lane = tid & 63;
  const int wave = tid >> 6;
  const int rbase = blockIdx.x * 16;
  const int sl   = blockIdx.y * 4 + wave;
  const int colL = lane & 15;
  const int g    = lane >> 4;
  const int kofs = g * 8;

  short8 aF[4];
  {
    const u16* ap = qb + (size_t)(rbase + colL) * D + kofs;
#pragma unroll
    for (int t = 0; t < 4; ++t) aF[t] = *reinterpret_cast<const short8*>(ap + t * 32);
  }

  float s[4][6]; int c[4][6];
#pragma unroll
  for (int r = 0; r < 4; ++r)
#pragma unroll
    for (int j = 0; j < 6; ++j) { s[r][j] = -3.0e38f; c[r][j] = 0x40000000 + colL * 6 + j; }

  const int tile0  = sl * 62 + (sl < 4 ? sl : 4);
  const int ntiles = 62 + (sl < 4 ? 1 : 0);
  const u16* bb = kb + (size_t)(tile0 * 16 + colL) * D + kofs;

  short8 bF[4];
#pragma unroll
  for (int t = 0; t < 4; ++t) bF[t] = *reinterpret_cast<const short8*>(bb + t * 32);

  for (int ct = 0; ct < ntiles; ++ct) {
    const int cn = (ct + 1 < ntiles) ? ct + 1 : ct;
    const u16* nb = bb + (size_t)cn * 16 * D;
    short8 bN[4];
#pragma unroll
    for (int t = 0; t < 4; ++t) bN[t] = *reinterpret_cast<const short8*>(nb + t * 32);

    f32x4 acc = {0.f, 0.f, 0.f, 0.f};
#pragma unroll
    for (int t = 0; t < 4; ++t)
      acc = __builtin_amdgcn_mfma_f32_16x16x32_bf16(aF[t], bF[t], acc, 0, 0, 0);

    const int colIdx = (tile0 + ct) * 16 + colL;
#pragma unroll
    for (int r = 0; r < 4; ++r) {
      float ks = acc[r]; int kc = colIdx;
      if (ks > s[r][5]) {
#pragma unroll
        for (int i = 0; i < 6; ++i) {
          const bool bgt = ks > s[r][i];
          const float os = s[r][i]; const int oc = c[r][i];
          s[r][i] = bgt ? ks : os;  c[r][i] = bgt ? kc : oc;
          ks      = bgt ? os : ks;  kc      = bgt ? oc : kc;
        }
      }
    }

#pragma unroll
    for (int t = 0; t < 4; ++t) bF[t] = bN[t];
  }

  u64 kk[4][6];
#pragma unroll
  for (int r = 0; r < 4; ++r)
#pragma unroll
    for (int j = 0; j < 6; ++j) {
      const u32 b = __builtin_bit_cast(u32, s[r][j]);
      const u32 mono = b ^ ((u32)(((int)b) >> 31) | 0x80000000u);
      kk[r][j] = ((u64)mono << 32) | (u64)(0xFFFFFFFFu - (u32)c[r][j]);
    }

  if (g < 2) {
#pragma unroll
    for (int r = 0; r < 4; ++r)
#pragma unroll
      for (int j = 0; j < 6; ++j)
        km[wave][4 * g + r][colL * 6 + j] = kk[r][j];
  }
  __syncthreads();
  if (g < 2) {
#pragma unroll
    for (int r = 0; r < 4; ++r) {
      int cnt[6] = {0, 0, 0, 0, 0, 0};
      for (int q2 = 0; q2 < 96; ++q2) {
        const u64 o = km[wave][4 * g + r][q2];
#pragma unroll
        for (int j = 0; j < 6; ++j) cnt[j] += (o > kk[r][j]) ? 1 : 0;
      }
      const int row = rbase + 4 * g + r;
#pragma unroll
      for (int j = 0; j < 6; ++j)
        if (cnt[j] < 16)
          cand[(size_t)row * 128 + sl * 16 + cnt[j]] = c[r][j];
    }
  }
  __syncthreads();
  if (g >= 2) {
#pragma unroll
    for (int r = 0; r < 4; ++r)
#pragma unroll
      for (int j = 0; j < 6; ++j)
        km[wave][4 * (g - 2) + r][colL * 6 + j] = kk[r][j];
  }
  __syncthreads();
  if (g >= 2) {
#pragma unroll
    for (int r = 0; r < 4; ++r) {
      int cnt[6] = {0, 0, 0, 0, 0, 0};
      for (int q2 = 0; q2 < 96; ++q2) {
        const u64 o = km[wave][4 * (g - 2) + r][q2];
#pragma unroll
        for (int j = 0; j < 6; ++j) cnt[j] += (o > kk[r][j]) ? 1 : 0;
      }
      const int row = rbase + 4 * g + r;
#pragma unroll
      for (int j = 0; j < 6; ++j)
        if (cnt[j] < 16)
          cand[(size_t)row * 128 + sl * 16 + cnt[j]] = c[r][j];
    }
  }
}

// ---------------------------------------------------------------------------
// Exact f32 rescore of 128 candidates (unchanged)
// ---------------------------------------------------------------------------
__global__ __launch_bounds__(64) void k_rescore128(const float* __restrict__ qn,
                                                   const float* __restrict__ kn,
                                                   const float* __restrict__ vn,
                                                   const int* __restrict__ cand,
                                                   float* __restrict__ enext) {
  const int row = blockIdx.x;
  const int lane = threadIdx.x;
  const int* cr = cand + (size_t)row * 128;
  const int c0 = cr[lane];
  const int c1 = cr[64 + lane];

  const float4* __restrict__ q4  = (const float4*)(qn + (size_t)row * D);
  const float4* __restrict__ k40 = (const float4*)(kn + (size_t)c0 * D);
  const float4* __restrict__ k41 = (const float4*)(kn + (size_t)c1 * D);
  float s0 = 0.f, s1 = 0.f;
#pragma unroll 8
  for (int j = 0; j < 32; ++j) {
    const float4 qv = q4[j];
    const float4 a = k40[j], b = k41[j];
    s0 = fmaf(qv.x, a.x, s0); s0 = fmaf(qv.y, a.y, s0);
    s0 = fmaf(qv.z, a.z, s0); s0 = fmaf(qv.w, a.w, s0);
    s1 = fmaf(qv.x, b.x, s1); s1 = fmaf(qv.y, b.y, s1);
    s1 = fmaf(qv.z, b.z, s1); s1 = fmaf(qv.w, b.w, s1);
  }
  const float inv = 0.088388347648318447f;   // 1/sqrt(128)
  s0 *= inv; s1 *= inv;

  int r0 = 0, r1 = 0;
  for (int j = 0; j < 64; ++j) {
    const float t0 = __shfl(s0, j), t1 = __shfl(s1, j);
    const int   u0 = __shfl(c0, j), u1 = __shfl(c1, j);
    r0 += (t0 > s0 || (t0 == s0 && u0 < c0)) ? 1 : 0;
    r0 += (t1 > s0 || (t1 == s0 && u1 < c0)) ? 1 : 0;
    r1 += (t0 > s1 || (t0 == s1 && u0 < c1)) ? 1 : 0;
    r1 += (t1 > s1 || (t1 == s1 && u1 < c1)) ? 1 : 0;
  }
  const bool sel0 = r0 < 16, sel1 = r1 < 16;

  float v = fmaxf(sel0 ? s0 : -3.0e38f, sel1 ? s1 : -3.0e38f);
#pragma unroll
  for (int d2 = 1; d2 < 64; d2 <<= 1) v = fmaxf(v, __shfl_xor(v, d2));
  const float e0 = sel0 ? expf(s0 - v) : 0.f;
  const float e1 = sel1 ? expf(s1 - v) : 0.f;
  float Z = e0 + e1;
#pragma unroll
  for (int d2 = 1; d2 < 64; d2 <<= 1) Z += __shfl_xor(Z, d2);
  const float w0 = e0 / Z, w1 = e1 / Z;

  float a0 = 0.f, a1 = 0.f;
  unsigned long long b0 = __ballot(sel0);
  while (b0) {
    const int src = __ffsll(b0) - 1; b0 &= b0 - 1;
    const float wj = __shfl(w0, src);
    const int   cj = __shfl(c0, src);
    const float* __restrict__ vr = vn + (size_t)cj * D;
    a0 = fmaf(wj, vr[lane], a0);
    a1 = fmaf(wj, vr[64 + lane], a1);
  }
  unsigned long long b1 = __ballot(sel1);
  while (b1) {
    const int src = __ffsll(b1) - 1; b1 &= b1 - 1;
    const float wj = __shfl(w1, src);
    const int   cj = __shfl(c1, src);
    const float* __restrict__ vr = vn + (size_t)cj * D;
    a0 = fmaf(wj, vr[lane], a0);
    a1 = fmaf(wj, vr[64 + lane], a1);
  }
  enext[(size_t)row * D + lane]      = fmaxf(a0, 0.f);
  enext[(size_t)row * D + 64 + lane] = fmaxf(a1, 0.f);
}

// ---------------------------------------------------------------------------
// final = [e0|e1|e2] @ la_w + la_b, row-L2-normalized (unchanged)
// ---------------------------------------------------------------------------
__global__ void k_final_norm(const float* __restrict__ e0, const float* __restrict__ e1,
                             const float* __restrict__ e2, const float* __restrict__ law,
                             const float* __restrict__ lab, float* __restrict__ out) {
  __shared__ float red[128];
  const int r = blockIdx.x;
  const int j = threadIdx.x;
  const float* __restrict__ a0 = e0 + (size_t)r * D;
  const float* __restrict__ a1 = e1 + (size_t)r * D;
  const float* __restrict__ a2 = e2 + (size_t)r * D;
  float acc = lab[j];
  for (int k = 0; k < D; ++k) acc = fmaf(a0[k], law[(size_t)k * D + j], acc);
  for (int k = 0; k < D; ++k) acc = fmaf(a1[k], law[(size_t)(D + k) * D + j], acc);
  for (int k = 0; k < D; ++k) acc = fmaf(a2[k], law[(size_t)(2 * D + k) * D + j], acc);
  red[j] = acc * acc;
  __syncthreads();
  for (int st = 64; st > 0; st >>= 1) {
    if (j < st) red[j] += red[j + st];
    __syncthreads();
  }
  const float nrm = fmaxf(sqrtf(red[0]), 1e-12f);
  const float o = acc / nrm;
  if (r < N_USERS) out[(size_t)r * D + j] = o;
  else             out[(size_t)N_USERS * D + (size_t)(r - N_USERS) * D + j] = o;
}

// ---------------------------------------------------------------------------
extern "C" void kernel_launch(void* const* d_in, const int* in_sizes, int n_in,
                              void* d_out, int out_size, void* d_ws, size_t ws_size,
                              hipStream_t stream) {
  const float* user_w = (const float*)d_in[0];
  const float* item_w = (const float*)d_in[1];
  const float* ent_w  = (const float*)d_in[2];
  const float* rel_w  = (const float*)d_in[3];
  const float* mfeat  = (const float*)d_in[4];
  const float* ufeat  = (const float*)d_in[5];
  const float* me_w1  = (const float*)d_in[6];
  const float* me_b1  = (const float*)d_in[7];
  const float* me_w2  = (const float*)d_in[8];
  const float* me_b2  = (const float*)d_in[9];
  const float* ue_w1  = (const float*)d_in[10];
  const float* ue_b1  = (const float*)d_in[11];
  const float* ue_w2  = (const float*)d_in[12];
  const float* ue_b2  = (const float*)d_in[13];
  const float* cm_vw  = (const float*)d_in[18];
  const float* cm_vb  = (const float*)d_in[19];
  const float* cm_ow  = (const float*)d_in[20];
  const float* cm_ob  = (const float*)d_in[21];
  const float* mg_w   = (const float*)d_in[22];
  const float* mg_b   = (const float*)d_in[23];
  const float* ug_w   = (const float*)d_in[24];
  const float* ug_b   = (const float*)d_in[25];
  const float* gnn_qw = (const float*)d_in[26];
  const float* gnn_qb = (const float*)d_in[27];
  const float* gnn_kw = (const float*)d_in[28];
  const float* gnn_kb = (const float*)d_in[29];
  const float* gnn_vw = (const float*)d_in[30];
  const float* gnn_vb = (const float*)d_in[31];
  const float* la_w   = (const float*)d_in[32];
  const float* la_b   = (const float*)d_in[33];
  const float* adj_d  = (const float*)d_in[34];
  const int*   adj_r  = (const int*)d_in[35];
  const int*   adj_c  = (const int*)d_in[36];
  float* out = (float*)d_out;
  float* ws  = (float*)d_ws;

  // ---- workspace layout (floats) ----
  size_t off = 0;
  float* mm_item = ws + off; off += (size_t)N_ITEMS * D;
  float* mm_user = ws + off; off += (size_t)N_USERS * D;
  float* enc     = ws + off; off += (size_t)N_ITEMS * D;
  float* tmp     = ws + off; off += (size_t)N_ITEMS * D;
  float* emb0    = ws + off; off += (size_t)NTOT * D;
  float* emb1    = ws + off; off += (size_t)NTOT * D;
  float* emb2    = ws + off; off += (size_t)NTOT * D;
  float* side    = ws + off; off += (size_t)NTOT * D;
  float* qn      = ws + off; off += (size_t)NTOT * D;
  float* kn      = ws + off; off += (size_t)NTOT * D;
  float* vn      = ws + off; off += (size_t)NTOT * D;
  float* relmean = ws + off; off += D;
  u16* arena = (u16*)(ws + off); off += 491520;
  u16* qb = (u16*)mm_user;
  u16* kb = qb + (size_t)NTOT * D;
  int* cand = (int*)side;
  int* rowptr = (int*)emb2;
  int* cursor = rowptr + 8064;
  int* permB  = cursor + 8064;

  // order: me_w1, me_w2, ue_w1, ue_w2, cm_vw, cm_ow, qw0, kw0, vw0, qw1, kw1, vw1
  static const int Ks[NMAT]  = {768, 128, 512, 128, 128, 128, 128, 128, 128, 128, 128, 128};
  int ofs[NMAT], cum[NMAT + 1];
  {
    int o = 0, cc = 0;
    for (int i = 0; i < NMAT; ++i) {
      ofs[i] = o; o += 3 * Ks[i] * 128;
      cum[i] = cc; cc += Ks[i] * 128;
    }
    cum[NMAT] = cc;
  }

  WsplitArgs wa;
  const float* wptr[NMAT] = {me_w1, me_w2, ue_w1, ue_w2, cm_vw, cm_ow,
                             gnn_qw, gnn_kw, gnn_vw,
                             gnn_qw + (size_t)D * D, gnn_kw + (size_t)D * D,
                             gnn_vw + (size_t)D * D};
  for (int i = 0; i < NMAT; ++i) {
    wa.w[i] = wptr[i];
    wa.useks[i] = (i == 7 || i == 10) ? 1 : 0;
    wa.K[i] = Ks[i];
    wa.cum[i] = cum[i];
    wa.ofs[i] = ofs[i];
  }
  wa.cum[NMAT] = cum[NMAT];

  k_relmean<<<1, D, 0, stream>>>(rel_w, relmean);
  k_wsplit_all<<<(cum[NMAT] + 255) / 256, 256, 0, stream>>>(wa, relmean, arena);

  // ---- modality encoders ----
  k_gemm3<<<(3000 + 63) / 64, 256, 0, stream>>>(mfeat, arena + ofs[0], me_b1, tmp, nullptr, 3000, 768, 1);
  k_gemm3<<<(3000 + 63) / 64, 256, 0, stream>>>(tmp, arena + ofs[1], me_b2, enc, nullptr, 3000, 128, 1);
  k_gemm3<<<(2500 + 63) / 64, 256, 0, stream>>>(ufeat, arena + ofs[2], ue_b1, tmp, nullptr, 2500, 512, 1);
  k_gemm3<<<(2500 + 63) / 64, 256, 0, stream>>>(tmp, arena + ofs[3], ue_b2, mm_user, nullptr, 2500, 128, 1);
  k_gemm3<<<(3000 + 63) / 64, 256, 0, stream>>>(enc, arena + ofs[4], cm_vb, tmp, nullptr, 3000, 128, 0);
  k_gemm3<<<(3000 + 63) / 64, 256, 0, stream>>>(tmp, arena + ofs[5], cm_ob, mm_item, nullptr, 3000, 128, 2);
  // ---- gated fusion -> emb0; copies fused ----
  k_gatefuse<<<N_ITEMS, D, 0, stream>>>(item_w, mm_item, mg_w, mg_b, emb0 + (size_t)N_USERS * D);
  k_gatefuse<<<N_USERS, D, 0, stream>>>(user_w, mm_user, ug_w, ug_b, emb0);
  k_copy3<<<(N_ITEMS * D + 255) / 256, 256, 0, stream>>>(
      ent_w, item_w, mm_item,
      emb0 + (size_t)(N_USERS + N_ITEMS) * D,
      out + (size_t)(N_USERS + N_ITEMS) * D,
      out + (size_t)(N_USERS + 2 * N_ITEMS) * D);

  // ---- CSR build ----
  hipMemsetAsync(cursor, 0, NTOT * sizeof(int), stream);
  k_hist<<<(NEDGE + 255) / 256, 256, 0, stream>>>(adj_r, cursor);
  k_scan<<<1, 1024, 0, stream>>>(cursor, rowptr, cursor);
  k_scatter<<<(NEDGE + 255) / 256, 256, 0, stream>>>(adj_r, cursor, permB);

  // ---- GNN layers ----
  const float* eml[3] = {emb0, emb1, emb2};
  for (int l = 0; l < 2; ++l) {
    const float* e = eml[l];
    float* enext   = (float*)eml[l + 1];
    k_spmm_csr<<<NTOT, 128, 0, stream>>>(adj_d, adj_c, permB, rowptr, e, side);
    k_gemm3<<<(NTOT + 63) / 64, 256, 0, stream>>>(e, arena + ofs[6 + 3 * l],
                                                  gnn_qb + (size_t)l * D, qn, qb, NTOT, 128, 0);
    k_gemm3x2<<<(NTOT + 63) / 64, 256, 0, stream>>>(side,
                                                    arena + ofs[7 + 3 * l], gnn_kb + (size_t)l * D, kn, kb,
                                                    arena + ofs[8 + 3 * l], gnn_vb + (size_t)l * D, vn,
                                                    NTOT, 128);
    dim3 tkgrid(NTOT / 16, 2);
    k_topk6v<<<tkgrid, 256, 0, stream>>>(qb, kb, cand);
    k_rescore128<<<NTOT, 64, 0, stream>>>(qn, kn, vn, cand, enext);
  }

  // ---- layer aggregation + normalize -> d_out ----
  k_final_norm<<<N_USERS + N_ITEMS, D, 0, stream>>>(emb0, emb1, emb2, la_w, la_b, out);
}

// Round 17
// 970.663 us; speedup vs baseline: 1.4116x; 1.1804x over previous
//
#include <hip/hip_runtime.h>
#include <hip/hip_bf16.h>
#include <math.h>

#define N_USERS 2500
#define N_ITEMS 3000
#define N_ENT   2500
#define NTOT    8000
#define D       128
#define NEDGE   256000
#define NSLICE  8
#define NMAT    12

typedef unsigned short u16;
typedef unsigned int u32;
typedef unsigned long long u64;
typedef __attribute__((ext_vector_type(8))) short short8;
typedef __attribute__((ext_vector_type(4))) float f32x4;

static __device__ __forceinline__ u16 bf16bits(float x) {
  __hip_bfloat16 h = __float2bfloat16(x);
  return *reinterpret_cast<u16*>(&h);
}

// ---------------------------------------------------------------------------
// One-shot W pre-split of all 12 weight matrices into a u16 arena.
// ---------------------------------------------------------------------------
struct WsplitArgs {
  const float* w[NMAT];
  int useks[NMAT];
  int K[NMAT];
  int cum[NMAT + 1];
  int ofs[NMAT];
};

__global__ void k_wsplit_all(WsplitArgs a, const float* __restrict__ relmean,
                             u16* __restrict__ arena) {
  const int e = blockIdx.x * 256 + threadIdx.x;
  if (e >= a.cum[NMAT]) return;
  int i = 0;
  while (e >= a.cum[i + 1]) ++i;
  const int local = e - a.cum[i];
  const int k = local >> 7, j = local & 127;
  const int K = a.K[i];
  float x = a.w[i][(size_t)k * 128 + j];
  if (a.useks[i]) x *= relmean[k];
  const __hip_bfloat16 h1 = __float2bfloat16(x);
  const float r1 = x - __bfloat162float(h1);
  const __hip_bfloat16 h2 = __float2bfloat16(r1);
  const float r2 = r1 - __bfloat162float(h2);
  const __hip_bfloat16 h3 = __float2bfloat16(r2);
  u16* __restrict__ base = arena + a.ofs[i] + (size_t)j * K + k;
  base[0]               = *(const u16*)&h1;
  base[(size_t)128 * K] = *(const u16*)&h2;
  base[(size_t)256 * K] = *(const u16*)&h3;
}

// ---------------------------------------------------------------------------
// MFMA GEMM core, f32-accurate via 3xbf16 splits (verified r11 body,
// factored into a device function; identical math & layout).
// ---------------------------------------------------------------------------
static __device__ __forceinline__ void gemm3_core(const float* __restrict__ A,
                                                  const u16* __restrict__ wsg,
                                                  const float* __restrict__ b,
                                                  float* __restrict__ out,
                                                  u16* __restrict__ ob,
                                                  int M, int K, int mode,
                                                  int bid, int tid) {
  const int lane = tid & 63;
  const int wave = tid >> 6;
  const int rbase = bid * 64 + wave * 16;
  const int colL = lane & 15;
  const int kofs = (lane >> 4) * 8;

  f32x4 acc[8];
#pragma unroll
  for (int ct = 0; ct < 8; ++ct) acc[ct] = (f32x4){0.f, 0.f, 0.f, 0.f};

  const int arow = (rbase + colL < M) ? (rbase + colL) : (M - 1);
  const float* __restrict__ arp = A + (size_t)arow * K;

  for (int k0 = 0; k0 < K; k0 += 32) {
    const float4 f0 = *(const float4*)(arp + k0 + kofs);
    const float4 f1 = *(const float4*)(arp + k0 + kofs + 4);
    float av[8] = {f0.x, f0.y, f0.z, f0.w, f1.x, f1.y, f1.z, f1.w};
    short8 a1, a2, a3;
#pragma unroll
    for (int e = 0; e < 8; ++e) {
      const float x = av[e];
      const __hip_bfloat16 h1 = __float2bfloat16(x);
      const float r1 = x - __bfloat162float(h1);
      const __hip_bfloat16 h2 = __float2bfloat16(r1);
      const float r2 = r1 - __bfloat162float(h2);
      const __hip_bfloat16 h3 = __float2bfloat16(r2);
      a1[e] = *(const short*)&h1;
      a2[e] = *(const short*)&h2;
      a3[e] = *(const short*)&h3;
    }
#pragma unroll
    for (int ct = 0; ct < 8; ++ct) {
      const int j = ct * 16 + colL;
      const u16* wp = wsg + (size_t)j * K + k0 + kofs;
      const short8 b1 = *(const short8*)wp;
      const short8 b2 = *(const short8*)(wp + (size_t)128 * K);
      const short8 b3 = *(const short8*)(wp + (size_t)256 * K);
      acc[ct] = __builtin_amdgcn_mfma_f32_16x16x32_bf16(a1, b1, acc[ct], 0, 0, 0);
      acc[ct] = __builtin_amdgcn_mfma_f32_16x16x32_bf16(a1, b2, acc[ct], 0, 0, 0);
      acc[ct] = __builtin_amdgcn_mfma_f32_16x16x32_bf16(a2, b1, acc[ct], 0, 0, 0);
      acc[ct] = __builtin_amdgcn_mfma_f32_16x16x32_bf16(a2, b2, acc[ct], 0, 0, 0);
      acc[ct] = __builtin_amdgcn_mfma_f32_16x16x32_bf16(a1, b3, acc[ct], 0, 0, 0);
      acc[ct] = __builtin_amdgcn_mfma_f32_16x16x32_bf16(a3, b1, acc[ct], 0, 0, 0);
    }
  }

#pragma unroll
  for (int ct = 0; ct < 8; ++ct) {
    const int j = ct * 16 + colL;
    const float bj = b[j];
#pragma unroll
    for (int r = 0; r < 4; ++r) {
      const int row = rbase + (lane >> 4) * 4 + r;
      if (row < M) {
        float c = acc[ct][r] + bj;
        if (mode == 1) c = fmaxf(c, 0.f);
        else if (mode == 2) c *= 2.f;
        out[(size_t)row * 128 + j] = c;
        if (ob) ob[(size_t)row * 128 + j] = bf16bits(c);
      }
    }
  }
}

__global__ __launch_bounds__(256) void k_gemm3(const float* __restrict__ A,
                                               const u16* __restrict__ wsg,
                                               const float* __restrict__ b,
                                               float* __restrict__ out,
                                               u16* __restrict__ ob,
                                               int M, int K, int mode) {
  gemm3_core(A, wsg, b, out, ob, M, K, mode, blockIdx.x, threadIdx.x);
}

// batched pair (both jobs, 64-row blocks, no bf16 mirror)
__global__ __launch_bounds__(256) void k_gemm3b(const float* A0, const u16* w0,
                                                const float* b0, float* o0, int M0, int K0, int nb0,
                                                const float* A1, const u16* w1,
                                                const float* b1, float* o1, int M1, int K1,
                                                int mode) {
  if ((int)blockIdx.x < nb0)
    gemm3_core(A0, w0, b0, o0, nullptr, M0, K0, mode, blockIdx.x, threadIdx.x);
  else
    gemm3_core(A1, w1, b1, o1, nullptr, M1, K1, mode, blockIdx.x - nb0, threadIdx.x);
}

// ---------------------------------------------------------------------------
// Wide-parallel GEMM for big-K encoders: 32 rows/block, 4 waves, each wave
// 16 rows x 4 col-tiles (2x wave count vs gemm3). Same math/layout.
// ---------------------------------------------------------------------------
static __device__ __forceinline__ void gemm3w_core(const float* __restrict__ A,
                                                   const u16* __restrict__ wsg,
                                                   const float* __restrict__ b,
                                                   float* __restrict__ out,
                                                   int M, int K, int mode,
                                                   int bid, int tid) {
  const int lane = tid & 63;
  const int wave = tid >> 6;
  const int rbase = bid * 32 + (wave & 1) * 16;
  const int ct0  = (wave >> 1) * 4;
  const int colL = lane & 15;
  const int kofs = (lane >> 4) * 8;

  f32x4 acc[4];
#pragma unroll
  for (int ct = 0; ct < 4; ++ct) acc[ct] = (f32x4){0.f, 0.f, 0.f, 0.f};

  const int arow = (rbase + colL < M) ? (rbase + colL) : (M - 1);
  const float* __restrict__ arp = A + (size_t)arow * K;

  for (int k0 = 0; k0 < K; k0 += 32) {
    const float4 f0 = *(const float4*)(arp + k0 + kofs);
    const float4 f1 = *(const float4*)(arp + k0 + kofs + 4);
    float av[8] = {f0.x, f0.y, f0.z, f0.w, f1.x, f1.y, f1.z, f1.w};
    short8 a1, a2, a3;
#pragma unroll
    for (int e = 0; e < 8; ++e) {
      const float x = av[e];
      const __hip_bfloat16 h1 = __float2bfloat16(x);
      const float r1 = x - __bfloat162float(h1);
      const __hip_bfloat16 h2 = __float2bfloat16(r1);
      const float r2 = r1 - __bfloat162float(h2);
      const __hip_bfloat16 h3 = __float2bfloat16(r2);
      a1[e] = *(const short*)&h1;
      a2[e] = *(const short*)&h2;
      a3[e] = *(const short*)&h3;
    }
#pragma unroll
    for (int ct = 0; ct < 4; ++ct) {
      const int j = (ct0 + ct) * 16 + colL;
      const u16* wp = wsg + (size_t)j * K + k0 + kofs;
      const short8 b1 = *(const short8*)wp;
      const short8 b2 = *(const short8*)(wp + (size_t)128 * K);
      const short8 b3 = *(const short8*)(wp + (size_t)256 * K);
      acc[ct] = __builtin_amdgcn_mfma_f32_16x16x32_bf16(a1, b1, acc[ct], 0, 0, 0);
      acc[ct] = __builtin_amdgcn_mfma_f32_16x16x32_bf16(a1, b2, acc[ct], 0, 0, 0);
      acc[ct] = __builtin_amdgcn_mfma_f32_16x16x32_bf16(a2, b1, acc[ct], 0, 0, 0);
      acc[ct] = __builtin_amdgcn_mfma_f32_16x16x32_bf16(a2, b2, acc[ct], 0, 0, 0);
      acc[ct] = __builtin_amdgcn_mfma_f32_16x16x32_bf16(a1, b3, acc[ct], 0, 0, 0);
      acc[ct] = __builtin_amdgcn_mfma_f32_16x16x32_bf16(a3, b1, acc[ct], 0, 0, 0);
    }
  }

#pragma unroll
  for (int ct = 0; ct < 4; ++ct) {
    const int j = (ct0 + ct) * 16 + colL;
    const float bj = b[j];
#pragma unroll
    for (int r = 0; r < 4; ++r) {
      const int row = rbase + (lane >> 4) * 4 + r;
      if (row < M) {
        float c = acc[ct][r] + bj;
        if (mode == 1) c = fmaxf(c, 0.f);
        else if (mode == 2) c *= 2.f;
        out[(size_t)row * 128 + j] = c;
      }
    }
  }
}

__global__ __launch_bounds__(256) void k_gemm3w2(const float* A0, const u16* w0,
                                                 const float* b0, float* o0, int M0, int K0, int nb0,
                                                 const float* A1, const u16* w1,
                                                 const float* b1, float* o1, int M1, int K1,
                                                 int mode) {
  if ((int)blockIdx.x < nb0)
    gemm3w_core(A0, w0, b0, o0, M0, K0, mode, blockIdx.x, threadIdx.x);
  else
    gemm3w_core(A1, w1, b1, o1, M1, K1, mode, blockIdx.x - nb0, threadIdx.x);
}

// ---------------------------------------------------------------------------
// Dual-B MFMA GEMM (kn+vn share A) — verified r14 (unchanged)
// ---------------------------------------------------------------------------
__global__ __launch_bounds__(256) void k_gemm3x2(const float* __restrict__ A,
                                                 const u16* __restrict__ wsgA,
                                                 const float* __restrict__ bA,
                                                 float* __restrict__ outA,
                                                 u16* __restrict__ obA,
                                                 const u16* __restrict__ wsgB,
                                                 const float* __restrict__ bB,
                                                 float* __restrict__ outB,
                                                 int M, int K) {
  const int tid  = threadIdx.x;
  const int lane = tid & 63;
  const int wave = tid >> 6;
  const int rbase = blockIdx.x * 64 + wave * 16;
  const int colL = lane & 15;
  const int kofs = (lane >> 4) * 8;

  f32x4 accA[8], accB[8];
#pragma unroll
  for (int ct = 0; ct < 8; ++ct) {
    accA[ct] = (f32x4){0.f, 0.f, 0.f, 0.f};
    accB[ct] = (f32x4){0.f, 0.f, 0.f, 0.f};
  }

  const int arow = (rbase + colL < M) ? (rbase + colL) : (M - 1);
  const float* __restrict__ arp = A + (size_t)arow * K;

  for (int k0 = 0; k0 < K; k0 += 32) {
    const float4 f0 = *(const float4*)(arp + k0 + kofs);
    const float4 f1 = *(const float4*)(arp + k0 + kofs + 4);
    float av[8] = {f0.x, f0.y, f0.z, f0.w, f1.x, f1.y, f1.z, f1.w};
    short8 a1, a2, a3;
#pragma unroll
    for (int e = 0; e < 8; ++e) {
      const float x = av[e];
      const __hip_bfloat16 h1 = __float2bfloat16(x);
      const float r1 = x - __bfloat162float(h1);
      const __hip_bfloat16 h2 = __float2bfloat16(r1);
      const float r2 = r1 - __bfloat162float(h2);
      const __hip_bfloat16 h3 = __float2bfloat16(r2);
      a1[e] = *(const short*)&h1;
      a2[e] = *(const short*)&h2;
      a3[e] = *(const short*)&h3;
    }
#pragma unroll
    for (int ct = 0; ct < 8; ++ct) {
      const int j = ct * 16 + colL;
      {
        const u16* wp = wsgA + (size_t)j * K + k0 + kofs;
        const short8 b1 = *(const short8*)wp;
        const short8 b2 = *(const short8*)(wp + (size_t)128 * K);
        const short8 b3 = *(const short8*)(wp + (size_t)256 * K);
        accA[ct] = __builtin_amdgcn_mfma_f32_16x16x32_bf16(a1, b1, accA[ct], 0, 0, 0);
        accA[ct] = __builtin_amdgcn_mfma_f32_16x16x32_bf16(a1, b2, accA[ct], 0, 0, 0);
        accA[ct] = __builtin_amdgcn_mfma_f32_16x16x32_bf16(a2, b1, accA[ct], 0, 0, 0);
        accA[ct] = __builtin_amdgcn_mfma_f32_16x16x32_bf16(a2, b2, accA[ct], 0, 0, 0);
        accA[ct] = __builtin_amdgcn_mfma_f32_16x16x32_bf16(a1, b3, accA[ct], 0, 0, 0);
        accA[ct] = __builtin_amdgcn_mfma_f32_16x16x32_bf16(a3, b1, accA[ct], 0, 0, 0);
      }
      {
        const u16* wp = wsgB + (size_t)j * K + k0 + kofs;
        const short8 b1 = *(const short8*)wp;
        const short8 b2 = *(const short8*)(wp + (size_t)128 * K);
        const short8 b3 = *(const short8*)(wp + (size_t)256 * K);
        accB[ct] = __builtin_amdgcn_mfma_f32_16x16x32_bf16(a1, b1, accB[ct], 0, 0, 0);
        accB[ct] = __builtin_amdgcn_mfma_f32_16x16x32_bf16(a1, b2, accB[ct], 0, 0, 0);
        accB[ct] = __builtin_amdgcn_mfma_f32_16x16x32_bf16(a2, b1, accB[ct], 0, 0, 0);
        accB[ct] = __builtin_amdgcn_mfma_f32_16x16x32_bf16(a2, b2, accB[ct], 0, 0, 0);
        accB[ct] = __builtin_amdgcn_mfma_f32_16x16x32_bf16(a1, b3, accB[ct], 0, 0, 0);
        accB[ct] = __builtin_amdgcn_mfma_f32_16x16x32_bf16(a3, b1, accB[ct], 0, 0, 0);
      }
    }
  }

#pragma unroll
  for (int ct = 0; ct < 8; ++ct) {
    const int j = ct * 16 + colL;
    const float bjA = bA[j];
    const float bjB = bB[j];
#pragma unroll
    for (int r = 0; r < 4; ++r) {
      const int row = rbase + (lane >> 4) * 4 + r;
      if (row < M) {
        const float cA = accA[ct][r] + bjA;
        outA[(size_t)row * 128 + j] = cA;
        obA[(size_t)row * 128 + j] = bf16bits(cA);
        outB[(size_t)row * 128 + j] = accB[ct][r] + bjB;
      }
    }
  }
}

// ---------------------------------------------------------------------------
// Merged gated fusion (user rows then item rows; one launch)
// ---------------------------------------------------------------------------
__global__ void k_gatefuse2(const float* __restrict__ user_w, const float* __restrict__ mm_user,
                            const float* __restrict__ ug_w, const float* __restrict__ ug_b,
                            const float* __restrict__ item_w, const float* __restrict__ mm_item,
                            const float* __restrict__ mg_w, const float* __restrict__ mg_b,
                            float* __restrict__ emb0) {
  const int r = blockIdx.x;
  const int j = threadIdx.x;
  const float* b0; const float* m0; const float* gw; const float* gb;
  if (r < N_USERS) {
    b0 = user_w + (size_t)r * D; m0 = mm_user + (size_t)r * D; gw = ug_w; gb = ug_b;
  } else {
    const int ri = r - N_USERS;
    b0 = item_w + (size_t)ri * D; m0 = mm_item + (size_t)ri * D; gw = mg_w; gb = mg_b;
  }
  float acc = 0.f;
  for (int k = 0; k < D; ++k) acc = fmaf(b0[k], gw[(size_t)k * D + j], acc);
  for (int k = 0; k < D; ++k) acc = fmaf(m0[k], gw[(size_t)(D + k) * D + j], acc);
  acc += gb[j];
  const float s1 = 1.f / (1.f + expf(-acc));
  const float g  = 1.f / (1.f + expf(-(s1 * 2.f)));
  const float bv = b0[j], mv = m0[j];
  emb0[(size_t)r * D + j] = g * bv + (1.f - g) * mv + 0.1f * bv;
}

__global__ void k_relmean(const float* __restrict__ rel, float* __restrict__ out) {
  const int j = threadIdx.x;
  float s = 0.f;
  for (int i = 0; i < 32; ++i) s += rel[i * D + j];
  out[j] = s * (1.f / 32.f);
}

__global__ void k_copy3(const float* __restrict__ ent, const float* __restrict__ item,
                        const float* __restrict__ mm, float* __restrict__ emb0ent,
                        float* __restrict__ outItem, float* __restrict__ outMM) {
  const int t = blockIdx.x * 256 + threadIdx.x;
  const int nEnt = N_ENT * D;
  const int nIt  = N_ITEMS * D;
  if (t < nEnt) emb0ent[t] = ent[t];
  if (t < nIt) {
    outItem[t] = item[t];
    outMM[t]   = mm[t];
  }
}

// ---------------------------------------------------------------------------
// CSR build (unchanged from r13)
// ---------------------------------------------------------------------------
__global__ void k_hist(const int* __restrict__ rw, int* __restrict__ cnt) {
  const int e = blockIdx.x * 256 + threadIdx.x;
  if (e < NEDGE) atomicAdd(&cnt[rw[e]], 1);
}

__global__ __launch_bounds__(1024) void k_scan(int* __restrict__ cnt,
                                               int* __restrict__ rowptr,
                                               int* __restrict__ cursor) {
  __shared__ int part[1024];
  const int t = threadIdx.x;
  const int base = t * 8;
  int loc[8];
  int s = 0;
#pragma unroll
  for (int j = 0; j < 8; ++j) {
    const int v = (base + j < NTOT) ? cnt[base + j] : 0;
    loc[j] = s; s += v;
  }
  part[t] = s;
  __syncthreads();
  for (int off = 1; off < 1024; off <<= 1) {
    const int v = (t >= off) ? part[t - off] : 0;
    __syncthreads();
    part[t] += v;
    __syncthreads();
  }
  const int pre = (t == 0) ? 0 : part[t - 1];
#pragma unroll
  for (int j = 0; j < 8; ++j) {
    if (base + j < NTOT) {
      const int p = pre + loc[j];
      rowptr[base + j] = p;
      cursor[base + j] = p;
    }
  }
  if (t == 1023) rowptr[NTOT] = part[1023];
}

__global__ void k_scatter(const int* __restrict__ rw, int* __restrict__ cursor,
                          int* __restrict__ perm) {
  const int e = blockIdx.x * 256 + threadIdx.x;
  if (e >= NEDGE) return;
  const int pos = atomicAdd(&cursor[rw[e]], 1);
  perm[pos] = e;
}

__global__ __launch_bounds__(128) void k_spmm_csr(const float* __restrict__ dat,
                                                  const int* __restrict__ cl,
                                                  const int* __restrict__ perm,
                                                  const int* __restrict__ rowptr,
                                                  const float* __restrict__ emb,
                                                  float* __restrict__ side) {
  const int r = blockIdx.x;
  const int d = threadIdx.x;
  const int beg = rowptr[r], end = rowptr[r + 1];
  float acc = 0.f;
  for (int i = beg; i < end; ++i) {
    const int ei = perm[i];
    acc = fmaf(dat[ei], emb[(size_t)cl[ei] * D + d], acc);
  }
  side[(size_t)r * D + d] = acc;
}

// ---------------------------------------------------------------------------
// bf16-MFMA score scan + shuffle-free top selection (r12 version, PROVEN,
// byte-identical)
// ---------------------------------------------------------------------------
__global__ __launch_bounds__(256) void k_topk6v(const u16* __restrict__ qb,
                                                const u16* __restrict__ kb,
                                                int* __restrict__ cand) {
  __shared__ u64 km[4][8][97];
  const int tid  = threadIdx.x;
  const int lane = tid & 63;
  const int wave = tid >> 6;
  const int rbase = blockIdx.x * 16;
  const int sl   = blockIdx.y * 4 + wave;
  const int colL = lane & 15;
  const int g    = lane >> 4;
  const int kofs = g * 8;

  short8 aF[4];
  {
    const u16* ap = qb + (size_t)(rbase + colL) * D + kofs;
#pragma unroll
    for (int t = 0; t < 4; ++t) aF[t] = *reinterpret_cast<const short8*>(ap + t * 32);
  }

  float s[4][6]; int c[4][6];
#pragma unroll
  for (int r = 0; r < 4; ++r)
#pragma unroll
    for (int j = 0; j < 6; ++j) { s[r][j] = -3.0e38f; c[r][j] = 0x40000000 + colL * 6 + j; }

  const int tile0  = sl * 62 + (sl < 4 ? sl : 4);
  const int ntiles = 62 + (sl < 4 ? 1 : 0);
  const u16* bb = kb + (size_t)(tile0 * 16 + colL) * D + kofs;

  short8 bF[4];
#pragma unroll
  for (int t = 0; t < 4; ++t) bF[t] = *reinterpret_cast<const short8*>(bb + t * 32);

  for (int ct = 0; ct < ntiles; ++ct) {
    const int cn = (ct + 1 < ntiles) ? ct + 1 : ct;
    const u16* nb = bb + (size_t)cn * 16 * D;
    short8 bN[4];
#pragma unroll
    for (int t = 0; t < 4; ++t) bN[t] = *reinterpret_cast<const short8*>(nb + t * 32);

    f32x4 acc = {0.f, 0.f, 0.f, 0.f};
#pragma unroll
    for (int t = 0; t < 4; ++t)
      acc = __builtin_amdgcn_mfma_f32_16x16x32_bf16(aF[t], bF[t], acc, 0, 0, 0);

    const int colIdx = (tile0 + ct) * 16 + colL;
#pragma unroll
    for (int r = 0; r < 4; ++r) {
      float ks = acc[r]; int kc = colIdx;
      if (ks > s[r][5]) {
#pragma unroll
        for (int i = 0; i < 6; ++i) {
          const bool bgt = ks > s[r][i];
          const float os = s[r][i]; const int oc = c[r][i];
          s[r][i] = bgt ? ks : os;  c[r][i] = bgt ? kc : oc;
          ks      = bgt ? os : ks;  kc      = bgt ? oc : kc;
        }
      }
    }

#pragma unroll
    for (int t = 0; t < 4; ++t) bF[t] = bN[t];
  }

  u64 kk[4][6];
#pragma unroll
  for (int r = 0; r < 4; ++r)
#pragma unroll
    for (int j = 0; j < 6; ++j) {
      const u32 b = __builtin_bit_cast(u32, s[r][j]);
      const u32 mono = b ^ ((u32)(((int)b) >> 31) | 0x80000000u);
      kk[r][j] = ((u64)mono << 32) | (u64)(0xFFFFFFFFu - (u32)c[r][j]);
    }

  if (g < 2) {
#pragma unroll
    for (int r = 0; r < 4; ++r)
#pragma unroll
      for (int j = 0; j < 6; ++j)
        km[wave][4 * g + r][colL * 6 + j] = kk[r][j];
  }
  __syncthreads();
  if (g < 2) {
#pragma unroll
    for (int r = 0; r < 4; ++r) {
      int cnt[6] = {0, 0, 0, 0, 0, 0};
      for (int q2 = 0; q2 < 96; ++q2) {
        const u64 o = km[wave][4 * g + r][q2];
#pragma unroll
        for (int j = 0; j < 6; ++j) cnt[j] += (o > kk[r][j]) ? 1 : 0;
      }
      const int row = rbase + 4 * g + r;
#pragma unroll
      for (int j = 0; j < 6; ++j)
        if (cnt[j] < 16)
          cand[(size_t)row * 128 + sl * 16 + cnt[j]] = c[r][j];
    }
  }
  __syncthreads();
  if (g >= 2) {
#pragma unroll
    for (int r = 0; r < 4; ++r)
#pragma unroll
      for (int j = 0; j < 6; ++j)
        km[wave][4 * (g - 2) + r][colL * 6 + j] = kk[r][j];
  }
  __syncthreads();
  if (g >= 2) {
#pragma unroll
    for (int r = 0; r < 4; ++r) {
      int cnt[6] = {0, 0, 0, 0, 0, 0};
      for (int q2 = 0; q2 < 96; ++q2) {
        const u64 o = km[wave][4 * (g - 2) + r][q2];
#pragma unroll
        for (int j = 0; j < 6; ++j) cnt[j] += (o > kk[r][j]) ? 1 : 0;
      }
      const int row = rbase + 4 * g + r;
#pragma unroll
      for (int j = 0; j < 6; ++j)
        if (cnt[j] < 16)
          cand[(size_t)row * 128 + sl * 16 + cnt[j]] = c[r][j];
    }
  }
}

// ---------------------------------------------------------------------------
// Exact f32 rescore of 128 candidates. r17: the 64-iter shuffle rank is
// replaced by an LDS count over 128 exact packed u64 keys (r10-proven
// packing; keys distinct since slices partition columns). Same comparator
// (value desc, index asc); softmax + gather paths unchanged.
// ---------------------------------------------------------------------------
__global__ __launch_bounds__(64) void k_rescore128(const float* __restrict__ qn,
                                                   const float* __restrict__ kn,
                                                   const float* __restrict__ vn,
                                                   const int* __restrict__ cand,
                                                   float* __restrict__ enext) {
  __shared__ u64 skey[128];
  const int row = blockIdx.x;
  const int lane = threadIdx.x;
  const int* cr = cand + (size_t)row * 128;
  const int c0 = cr[lane];
  const int c1 = cr[64 + lane];

  const float4* __restrict__ q4  = (const float4*)(qn + (size_t)row * D);
  const float4* __restrict__ k40 = (const float4*)(kn + (size_t)c0 * D);
  const float4* __restrict__ k41 = (const float4*)(kn + (size_t)c1 * D);
  float s0 = 0.f, s1 = 0.f;
#pragma unroll 8
  for (int j = 0; j < 32; ++j) {
    const float4 qv = q4[j];
    const float4 a = k40[j], b = k41[j];
    s0 = fmaf(qv.x, a.x, s0); s0 = fmaf(qv.y, a.y, s0);
    s0 = fmaf(qv.z, a.z, s0); s0 = fmaf(qv.w, a.w, s0);
    s1 = fmaf(qv.x, b.x, s1); s1 = fmaf(qv.y, b.y, s1);
    s1 = fmaf(qv.z, b.z, s1); s1 = fmaf(qv.w, b.w, s1);
  }
  const float inv = 0.088388347648318447f;   // 1/sqrt(128)
  s0 *= inv; s1 *= inv;

  // exact packed keys: (mono(score) << 32) | (0xFFFFFFFF - col)
  const u32 b0i = __builtin_bit_cast(u32, s0);
  const u32 b1i = __builtin_bit_cast(u32, s1);
  const u64 key0 = ((u64)(b0i ^ ((u32)(((int)b0i) >> 31) | 0x80000000u)) << 32)
                   | (u64)(0xFFFFFFFFu - (u32)c0);
  const u64 key1 = ((u64)(b1i ^ ((u32)(((int)b1i) >> 31) | 0x80000000u)) << 32)
                   | (u64)(0xFFFFFFFFu - (u32)c1);
  skey[lane] = key0;
  skey[64 + lane] = key1;
  __syncthreads();

  int r0 = 0, r1 = 0;
#pragma unroll 8
  for (int j = 0; j < 128; ++j) {
    const u64 o = skey[j];
    r0 += (o > key0) ? 1 : 0;
    r1 += (o > key1) ? 1 : 0;
  }
  const bool sel0 = r0 < 16, sel1 = r1 < 16;

  float v = fmaxf(sel0 ? s0 : -3.0e38f, sel1 ? s1 : -3.0e38f);
#pragma unroll
  for (int d2 = 1; d2 < 64; d2 <<= 1) v = fmaxf(v, __shfl_xor(v, d2));
  const float e0 = sel0 ? expf(s0 - v) : 0.f;
  const float e1 = sel1 ? expf(s1 - v) : 0.f;
  float Z = e0 + e1;
#pragma unroll
  for (int d2 = 1; d2 < 64; d2 <<= 1) Z += __shfl_xor(Z, d2);
  const float w0 = e0 / Z, w1 = e1 / Z;

  float a0 = 0.f, a1 = 0.f;
  unsigned long long bm0 = __ballot(sel0);
  while (bm0) {
    const int src = __ffsll(bm0) - 1; bm0 &= bm0 - 1;
    const float wj = __shfl(w0, src);
    const int   cj = __shfl(c0, src);
    const float* __restrict__ vr = vn + (size_t)cj * D;
    a0 = fmaf(wj, vr[lane], a0);
    a1 = fmaf(wj, vr[64 + lane], a1);
  }
  unsigned long long bm1 = __ballot(sel1);
  while (bm1) {
    const int src = __ffsll(bm1) - 1; bm1 &= bm1 - 1;
    const float wj = __shfl(w1, src);
    const int   cj = __shfl(c1, src);
    const float* __restrict__ vr = vn + (size_t)cj * D;
    a0 = fmaf(wj, vr[lane], a0);
    a1 = fmaf(wj, vr[64 + lane], a1);
  }
  enext[(size_t)row * D + lane]      = fmaxf(a0, 0.f);
  enext[(size_t)row * D + 64 + lane] = fmaxf(a1, 0.f);
}

// ---------------------------------------------------------------------------
// final = [e0|e1|e2] @ la_w + la_b, row-L2-normalized (unchanged)
// ---------------------------------------------------------------------------
__global__ void k_final_norm(const float* __restrict__ e0, const float* __restrict__ e1,
                             const float* __restrict__ e2, const float* __restrict__ law,
                             const float* __restrict__ lab, float* __restrict__ out) {
  __shared__ float red[128];
  const int r = blockIdx.x;
  const int j = threadIdx.x;
  const float* __restrict__ a0 = e0 + (size_t)r * D;
  const float* __restrict__ a1 = e1 + (size_t)r * D;
  const float* __restrict__ a2 = e2 + (size_t)r * D;
  float acc = lab[j];
  for (int k = 0; k < D; ++k) acc = fmaf(a0[k], law[(size_t)k * D + j], acc);
  for (int k = 0; k < D; ++k) acc = fmaf(a1[k], law[(size_t)(D + k) * D + j], acc);
  for (int k = 0; k < D; ++k) acc = fmaf(a2[k], law[(size_t)(2 * D + k) * D + j], acc);
  red[j] = acc * acc;
  __syncthreads();
  for (int st = 64; st > 0; st >>= 1) {
    if (j < st) red[j] += red[j + st];
    __syncthreads();
  }
  const float nrm = fmaxf(sqrtf(red[0]), 1e-12f);
  const float o = acc / nrm;
  if (r < N_USERS) out[(size_t)r * D + j] = o;
  else             out[(size_t)N_USERS * D + (size_t)(r - N_USERS) * D + j] = o;
}

// ---------------------------------------------------------------------------
extern "C" void kernel_launch(void* const* d_in, const int* in_sizes, int n_in,
                              void* d_out, int out_size, void* d_ws, size_t ws_size,
                              hipStream_t stream) {
  const float* user_w = (const float*)d_in[0];
  const float* item_w = (const float*)d_in[1];
  const float* ent_w  = (const float*)d_in[2];
  const float* rel_w  = (const float*)d_in[3];
  const float* mfeat  = (const float*)d_in[4];
  const float* ufeat  = (const float*)d_in[5];
  const float* me_w1  = (const float*)d_in[6];
  const float* me_b1  = (const float*)d_in[7];
  const float* me_w2  = (const float*)d_in[8];
  const float* me_b2  = (const float*)d_in[9];
  const float* ue_w1  = (const float*)d_in[10];
  const float* ue_b1  = (const float*)d_in[11];
  const float* ue_w2  = (const float*)d_in[12];
  const float* ue_b2  = (const float*)d_in[13];
  const float* cm_vw  = (const float*)d_in[18];
  const float* cm_vb  = (const float*)d_in[19];
  const float* cm_ow  = (const float*)d_in[20];
  const float* cm_ob  = (const float*)d_in[21];
  const float* mg_w   = (const float*)d_in[22];
  const float* mg_b   = (const float*)d_in[23];
  const float* ug_w   = (const float*)d_in[24];
  const float* ug_b   = (const float*)d_in[25];
  const float* gnn_qw = (const float*)d_in[26];
  const float* gnn_qb = (const float*)d_in[27];
  const float* gnn_kw = (const float*)d_in[28];
  const float* gnn_kb = (const float*)d_in[29];
  const float* gnn_vw = (const float*)d_in[30];
  const float* gnn_vb = (const float*)d_in[31];
  const float* la_w   = (const float*)d_in[32];
  const float* la_b   = (const float*)d_in[33];
  const float* adj_d  = (const float*)d_in[34];
  const int*   adj_r  = (const int*)d_in[35];
  const int*   adj_c  = (const int*)d_in[36];
  float* out = (float*)d_out;
  float* ws  = (float*)d_ws;

  // ---- workspace layout (floats) ----
  size_t off = 0;
  float* mm_item = ws + off; off += (size_t)N_ITEMS * D;
  float* mm_user = ws + off; off += (size_t)N_USERS * D;
  float* enc     = ws + off; off += (size_t)N_ITEMS * D;
  float* tmp     = ws + off; off += (size_t)N_ITEMS * D;
  float* emb0    = ws + off; off += (size_t)NTOT * D;
  float* emb1    = ws + off; off += (size_t)NTOT * D;
  float* emb2    = ws + off; off += (size_t)NTOT * D;
  float* side    = ws + off; off += (size_t)NTOT * D;
  float* qn      = ws + off; off += (size_t)NTOT * D;
  float* kn      = ws + off; off += (size_t)NTOT * D;
  float* vn      = ws + off; off += (size_t)NTOT * D;
  float* relmean = ws + off; off += D;
  u16* arena = (u16*)(ws + off); off += 491520;
  u16* qb = (u16*)mm_user;
  u16* kb = qb + (size_t)NTOT * D;
  int* cand = (int*)side;
  int* rowptr = (int*)emb2;
  int* cursor = rowptr + 8064;
  int* permB  = cursor + 8064;
  // user hidden layer lives in `side` (dead until first spmm)
  float* utmp = side;

  // order: me_w1, me_w2, ue_w1, ue_w2, cm_vw, cm_ow, qw0, kw0, vw0, qw1, kw1, vw1
  static const int Ks[NMAT]  = {768, 128, 512, 128, 128, 128, 128, 128, 128, 128, 128, 128};
  int ofs[NMAT], cum[NMAT + 1];
  {
    int o = 0, cc = 0;
    for (int i = 0; i < NMAT; ++i) {
      ofs[i] = o; o += 3 * Ks[i] * 128;
      cum[i] = cc; cc += Ks[i] * 128;
    }
    cum[NMAT] = cc;
  }

  WsplitArgs wa;
  const float* wptr[NMAT] = {me_w1, me_w2, ue_w1, ue_w2, cm_vw, cm_ow,
                             gnn_qw, gnn_kw, gnn_vw,
                             gnn_qw + (size_t)D * D, gnn_kw + (size_t)D * D,
                             gnn_vw + (size_t)D * D};
  for (int i = 0; i < NMAT; ++i) {
    wa.w[i] = wptr[i];
    wa.useks[i] = (i == 7 || i == 10) ? 1 : 0;
    wa.K[i] = Ks[i];
    wa.cum[i] = cum[i];
    wa.ofs[i] = ofs[i];
  }
  wa.cum[NMAT] = cum[NMAT];

  k_relmean<<<1, D, 0, stream>>>(rel_w, relmean);
  k_wsplit_all<<<(cum[NMAT] + 255) / 256, 256, 0, stream>>>(wa, relmean, arena);

  // ---- modality encoders: batched item+user chains ----
  const int nbI1 = (3000 + 31) / 32;   // 94
  const int nbU1 = (2500 + 31) / 32;   // 79
  k_gemm3w2<<<nbI1 + nbU1, 256, 0, stream>>>(
      mfeat, arena + ofs[0], me_b1, tmp,  3000, 768, nbI1,
      ufeat, arena + ofs[2], ue_b1, utmp, 2500, 512, 1);
  const int nbI2 = (3000 + 63) / 64;   // 47
  const int nbU2 = (2500 + 63) / 64;   // 40
  k_gemm3b<<<nbI2 + nbU2, 256, 0, stream>>>(
      tmp,  arena + ofs[1], me_b2, enc,     3000, 128, nbI2,
      utmp, arena + ofs[3], ue_b2, mm_user, 2500, 128, 1);
  // ---- collapsed cross-modal attention: mm_item = 2*((enc@vw+vb)@ow+ob) ----
  k_gemm3<<<(3000 + 63) / 64, 256, 0, stream>>>(enc, arena + ofs[4], cm_vb, tmp, nullptr, 3000, 128, 0);
  k_gemm3<<<(3000 + 63) / 64, 256, 0, stream>>>(tmp, arena + ofs[5], cm_ob, mm_item, nullptr, 3000, 128, 2);
  // ---- gated fusion (merged) -> emb0; copies fused ----
  k_gatefuse2<<<N_USERS + N_ITEMS, D, 0, stream>>>(user_w, mm_user, ug_w, ug_b,
                                                   item_w, mm_item, mg_w, mg_b, emb0);
  k_copy3<<<(N_ITEMS * D + 255) / 256, 256, 0, stream>>>(
      ent_w, item_w, mm_item,
      emb0 + (size_t)(N_USERS + N_ITEMS) * D,
      out + (size_t)(N_USERS + N_ITEMS) * D,
      out + (size_t)(N_USERS + 2 * N_ITEMS) * D);

  // ---- CSR build ----
  hipMemsetAsync(cursor, 0, NTOT * sizeof(int), stream);
  k_hist<<<(NEDGE + 255) / 256, 256, 0, stream>>>(adj_r, cursor);
  k_scan<<<1, 1024, 0, stream>>>(cursor, rowptr, cursor);
  k_scatter<<<(NEDGE + 255) / 256, 256, 0, stream>>>(adj_r, cursor, permB);

  // ---- GNN layers ----
  const float* eml[3] = {emb0, emb1, emb2};
  for (int l = 0; l < 2; ++l) {
    const float* e = eml[l];
    float* enext   = (float*)eml[l + 1];
    k_spmm_csr<<<NTOT, 128, 0, stream>>>(adj_d, adj_c, permB, rowptr, e, side);
    k_gemm3<<<(NTOT + 63) / 64, 256, 0, stream>>>(e, arena + ofs[6 + 3 * l],
                                                  gnn_qb + (size_t)l * D, qn, qb, NTOT, 128, 0);
    k_gemm3x2<<<(NTOT + 63) / 64, 256, 0, stream>>>(side,
                                                    arena + ofs[7 + 3 * l], gnn_kb + (size_t)l * D, kn, kb,
                                                    arena + ofs[8 + 3 * l], gnn_vb + (size_t)l * D, vn,
                                                    NTOT, 128);
    dim3 tkgrid(NTOT / 16, 2);
    k_topk6v<<<tkgrid, 256, 0, stream>>>(qb, kb, cand);
    k_rescore128<<<NTOT, 64, 0, stream>>>(qn, kn, vn, cand, enext);
  }

  // ---- layer aggregation + normalize -> d_out ----
  k_final_norm<<<N_USERS + N_ITEMS, D, 0, stream>>>(emb0, emb1, emb2, la_w, la_b, out);
}

// Round 18
// 920.247 us; speedup vs baseline: 1.4889x; 1.0548x over previous
//
#include <hip/hip_runtime.h>
#include <hip/hip_bf16.h>
#include <math.h>

#define N_USERS 2500
#define N_ITEMS 3000
#define N_ENT   2500
#define NTOT    8000
#define D       128
#define NEDGE   256000
#define NSLICE  8
#define NMAT    12

typedef unsigned short u16;
typedef unsigned int u32;
typedef unsigned long long u64;
typedef __attribute__((ext_vector_type(8))) short short8;
typedef __attribute__((ext_vector_type(4))) float f32x4;

static __device__ __forceinline__ u16 bf16bits(float x) {
  __hip_bfloat16 h = __float2bfloat16(x);
  return *reinterpret_cast<u16*>(&h);
}

// ---------------------------------------------------------------------------
// One-shot W pre-split of all 12 weight matrices into a u16 arena.
// ---------------------------------------------------------------------------
struct WsplitArgs {
  const float* w[NMAT];
  int useks[NMAT];
  int K[NMAT];
  int cum[NMAT + 1];
  int ofs[NMAT];
};

__global__ void k_wsplit_all(WsplitArgs a, const float* __restrict__ relmean,
                             u16* __restrict__ arena) {
  const int e = blockIdx.x * 256 + threadIdx.x;
  if (e >= a.cum[NMAT]) return;
  int i = 0;
  while (e >= a.cum[i + 1]) ++i;
  const int local = e - a.cum[i];
  const int k = local >> 7, j = local & 127;
  const int K = a.K[i];
  float x = a.w[i][(size_t)k * 128 + j];
  if (a.useks[i]) x *= relmean[k];
  const __hip_bfloat16 h1 = __float2bfloat16(x);
  const float r1 = x - __bfloat162float(h1);
  const __hip_bfloat16 h2 = __float2bfloat16(r1);
  const float r2 = r1 - __bfloat162float(h2);
  const __hip_bfloat16 h3 = __float2bfloat16(r2);
  u16* __restrict__ base = arena + a.ofs[i] + (size_t)j * K + k;
  base[0]               = *(const u16*)&h1;
  base[(size_t)128 * K] = *(const u16*)&h2;
  base[(size_t)256 * K] = *(const u16*)&h3;
}

// ---------------------------------------------------------------------------
// MFMA GEMM core, f32-accurate via 3xbf16 splits (verified r11 body).
// ---------------------------------------------------------------------------
static __device__ __forceinline__ void gemm3_core(const float* __restrict__ A,
                                                  const u16* __restrict__ wsg,
                                                  const float* __restrict__ b,
                                                  float* __restrict__ out,
                                                  u16* __restrict__ ob,
                                                  int M, int K, int mode,
                                                  int bid, int tid) {
  const int lane = tid & 63;
  const int wave = tid >> 6;
  const int rbase = bid * 64 + wave * 16;
  const int colL = lane & 15;
  const int kofs = (lane >> 4) * 8;

  f32x4 acc[8];
#pragma unroll
  for (int ct = 0; ct < 8; ++ct) acc[ct] = (f32x4){0.f, 0.f, 0.f, 0.f};

  const int arow = (rbase + colL < M) ? (rbase + colL) : (M - 1);
  const float* __restrict__ arp = A + (size_t)arow * K;

  for (int k0 = 0; k0 < K; k0 += 32) {
    const float4 f0 = *(const float4*)(arp + k0 + kofs);
    const float4 f1 = *(const float4*)(arp + k0 + kofs + 4);
    float av[8] = {f0.x, f0.y, f0.z, f0.w, f1.x, f1.y, f1.z, f1.w};
    short8 a1, a2, a3;
#pragma unroll
    for (int e = 0; e < 8; ++e) {
      const float x = av[e];
      const __hip_bfloat16 h1 = __float2bfloat16(x);
      const float r1 = x - __bfloat162float(h1);
      const __hip_bfloat16 h2 = __float2bfloat16(r1);
      const float r2 = r1 - __bfloat162float(h2);
      const __hip_bfloat16 h3 = __float2bfloat16(r2);
      a1[e] = *(const short*)&h1;
      a2[e] = *(const short*)&h2;
      a3[e] = *(const short*)&h3;
    }
#pragma unroll
    for (int ct = 0; ct < 8; ++ct) {
      const int j = ct * 16 + colL;
      const u16* wp = wsg + (size_t)j * K + k0 + kofs;
      const short8 b1 = *(const short8*)wp;
      const short8 b2 = *(const short8*)(wp + (size_t)128 * K);
      const short8 b3 = *(const short8*)(wp + (size_t)256 * K);
      acc[ct] = __builtin_amdgcn_mfma_f32_16x16x32_bf16(a1, b1, acc[ct], 0, 0, 0);
      acc[ct] = __builtin_amdgcn_mfma_f32_16x16x32_bf16(a1, b2, acc[ct], 0, 0, 0);
      acc[ct] = __builtin_amdgcn_mfma_f32_16x16x32_bf16(a2, b1, acc[ct], 0, 0, 0);
      acc[ct] = __builtin_amdgcn_mfma_f32_16x16x32_bf16(a2, b2, acc[ct], 0, 0, 0);
      acc[ct] = __builtin_amdgcn_mfma_f32_16x16x32_bf16(a1, b3, acc[ct], 0, 0, 0);
      acc[ct] = __builtin_amdgcn_mfma_f32_16x16x32_bf16(a3, b1, acc[ct], 0, 0, 0);
    }
  }

#pragma unroll
  for (int ct = 0; ct < 8; ++ct) {
    const int j = ct * 16 + colL;
    const float bj = b[j];
#pragma unroll
    for (int r = 0; r < 4; ++r) {
      const int row = rbase + (lane >> 4) * 4 + r;
      if (row < M) {
        float c = acc[ct][r] + bj;
        if (mode == 1) c = fmaxf(c, 0.f);
        else if (mode == 2) c *= 2.f;
        out[(size_t)row * 128 + j] = c;
        if (ob) ob[(size_t)row * 128 + j] = bf16bits(c);
      }
    }
  }
}

// Dual-B core (kn+vn share A) — verified r14 body, factored.
static __device__ __forceinline__ void gemm3x2_core(const float* __restrict__ A,
                                                    const u16* __restrict__ wsgA,
                                                    const float* __restrict__ bA,
                                                    float* __restrict__ outA,
                                                    u16* __restrict__ obA,
                                                    const u16* __restrict__ wsgB,
                                                    const float* __restrict__ bB,
                                                    float* __restrict__ outB,
                                                    int M, int K, int bid, int tid) {
  const int lane = tid & 63;
  const int wave = tid >> 6;
  const int rbase = bid * 64 + wave * 16;
  const int colL = lane & 15;
  const int kofs = (lane >> 4) * 8;

  f32x4 accA[8], accB[8];
#pragma unroll
  for (int ct = 0; ct < 8; ++ct) {
    accA[ct] = (f32x4){0.f, 0.f, 0.f, 0.f};
    accB[ct] = (f32x4){0.f, 0.f, 0.f, 0.f};
  }

  const int arow = (rbase + colL < M) ? (rbase + colL) : (M - 1);
  const float* __restrict__ arp = A + (size_t)arow * K;

  for (int k0 = 0; k0 < K; k0 += 32) {
    const float4 f0 = *(const float4*)(arp + k0 + kofs);
    const float4 f1 = *(const float4*)(arp + k0 + kofs + 4);
    float av[8] = {f0.x, f0.y, f0.z, f0.w, f1.x, f1.y, f1.z, f1.w};
    short8 a1, a2, a3;
#pragma unroll
    for (int e = 0; e < 8; ++e) {
      const float x = av[e];
      const __hip_bfloat16 h1 = __float2bfloat16(x);
      const float r1 = x - __bfloat162float(h1);
      const __hip_bfloat16 h2 = __float2bfloat16(r1);
      const float r2 = r1 - __bfloat162float(h2);
      const __hip_bfloat16 h3 = __float2bfloat16(r2);
      a1[e] = *(const short*)&h1;
      a2[e] = *(const short*)&h2;
      a3[e] = *(const short*)&h3;
    }
#pragma unroll
    for (int ct = 0; ct < 8; ++ct) {
      const int j = ct * 16 + colL;
      {
        const u16* wp = wsgA + (size_t)j * K + k0 + kofs;
        const short8 b1 = *(const short8*)wp;
        const short8 b2 = *(const short8*)(wp + (size_t)128 * K);
        const short8 b3 = *(const short8*)(wp + (size_t)256 * K);
        accA[ct] = __builtin_amdgcn_mfma_f32_16x16x32_bf16(a1, b1, accA[ct], 0, 0, 0);
        accA[ct] = __builtin_amdgcn_mfma_f32_16x16x32_bf16(a1, b2, accA[ct], 0, 0, 0);
        accA[ct] = __builtin_amdgcn_mfma_f32_16x16x32_bf16(a2, b1, accA[ct], 0, 0, 0);
        accA[ct] = __builtin_amdgcn_mfma_f32_16x16x32_bf16(a2, b2, accA[ct], 0, 0, 0);
        accA[ct] = __builtin_amdgcn_mfma_f32_16x16x32_bf16(a1, b3, accA[ct], 0, 0, 0);
        accA[ct] = __builtin_amdgcn_mfma_f32_16x16x32_bf16(a3, b1, accA[ct], 0, 0, 0);
      }
      {
        const u16* wp = wsgB + (size_t)j * K + k0 + kofs;
        const short8 b1 = *(const short8*)wp;
        const short8 b2 = *(const short8*)(wp + (size_t)128 * K);
        const short8 b3 = *(const short8*)(wp + (size_t)256 * K);
        accB[ct] = __builtin_amdgcn_mfma_f32_16x16x32_bf16(a1, b1, accB[ct], 0, 0, 0);
        accB[ct] = __builtin_amdgcn_mfma_f32_16x16x32_bf16(a1, b2, accB[ct], 0, 0, 0);
        accB[ct] = __builtin_amdgcn_mfma_f32_16x16x32_bf16(a2, b1, accB[ct], 0, 0, 0);
        accB[ct] = __builtin_amdgcn_mfma_f32_16x16x32_bf16(a2, b2, accB[ct], 0, 0, 0);
        accB[ct] = __builtin_amdgcn_mfma_f32_16x16x32_bf16(a1, b3, accB[ct], 0, 0, 0);
        accB[ct] = __builtin_amdgcn_mfma_f32_16x16x32_bf16(a3, b1, accB[ct], 0, 0, 0);
      }
    }
  }

#pragma unroll
  for (int ct = 0; ct < 8; ++ct) {
    const int j = ct * 16 + colL;
    const float bjA = bA[j];
    const float bjB = bB[j];
#pragma unroll
    for (int r = 0; r < 4; ++r) {
      const int row = rbase + (lane >> 4) * 4 + r;
      if (row < M) {
        const float cA = accA[ct][r] + bjA;
        outA[(size_t)row * 128 + j] = cA;
        obA[(size_t)row * 128 + j] = bf16bits(cA);
        outB[(size_t)row * 128 + j] = accB[ct][r] + bjB;
      }
    }
  }
}

__global__ __launch_bounds__(256) void k_gemm3(const float* __restrict__ A,
                                               const u16* __restrict__ wsg,
                                               const float* __restrict__ b,
                                               float* __restrict__ out,
                                               u16* __restrict__ ob,
                                               int M, int K, int mode) {
  gemm3_core(A, wsg, b, out, ob, M, K, mode, blockIdx.x, threadIdx.x);
}

// batched pair (both jobs, 64-row blocks, no bf16 mirror)
__global__ __launch_bounds__(256) void k_gemm3b(const float* A0, const u16* w0,
                                                const float* b0, float* o0, int M0, int K0, int nb0,
                                                const float* A1, const u16* w1,
                                                const float* b1, float* o1, int M1, int K1,
                                                int mode) {
  if ((int)blockIdx.x < nb0)
    gemm3_core(A0, w0, b0, o0, nullptr, M0, K0, mode, blockIdx.x, threadIdx.x);
  else
    gemm3_core(A1, w1, b1, o1, nullptr, M1, K1, mode, blockIdx.x - nb0, threadIdx.x);
}

// per-GNN-layer fused launch: qn (gemm3, with qb mirror) + kn/vn (gemm3x2)
__global__ __launch_bounds__(256) void k_gemm3qkv(const float* e, const u16* wq,
                                                  const float* bq, float* qn, u16* qb,
                                                  const float* side, const u16* wk,
                                                  const float* bk, float* kn, u16* kb,
                                                  const u16* wv, const float* bv, float* vn,
                                                  int M, int nb0) {
  if ((int)blockIdx.x < nb0)
    gemm3_core(e, wq, bq, qn, qb, M, 128, 0, blockIdx.x, threadIdx.x);
  else
    gemm3x2_core(side, wk, bk, kn, kb, wv, bv, vn, M, 128, blockIdx.x - nb0, threadIdx.x);
}

// ---------------------------------------------------------------------------
// Wide-parallel GEMM for big-K encoders (verified r17)
// ---------------------------------------------------------------------------
static __device__ __forceinline__ void gemm3w_core(const float* __restrict__ A,
                                                   const u16* __restrict__ wsg,
                                                   const float* __restrict__ b,
                                                   float* __restrict__ out,
                                                   int M, int K, int mode,
                                                   int bid, int tid) {
  const int lane = tid & 63;
  const int wave = tid >> 6;
  const int rbase = bid * 32 + (wave & 1) * 16;
  const int ct0  = (wave >> 1) * 4;
  const int colL = lane & 15;
  const int kofs = (lane >> 4) * 8;

  f32x4 acc[4];
#pragma unroll
  for (int ct = 0; ct < 4; ++ct) acc[ct] = (f32x4){0.f, 0.f, 0.f, 0.f};

  const int arow = (rbase + colL < M) ? (rbase + colL) : (M - 1);
  const float* __restrict__ arp = A + (size_t)arow * K;

  for (int k0 = 0; k0 < K; k0 += 32) {
    const float4 f0 = *(const float4*)(arp + k0 + kofs);
    const float4 f1 = *(const float4*)(arp + k0 + kofs + 4);
    float av[8] = {f0.x, f0.y, f0.z, f0.w, f1.x, f1.y, f1.z, f1.w};
    short8 a1, a2, a3;
#pragma unroll
    for (int e = 0; e < 8; ++e) {
      const float x = av[e];
      const __hip_bfloat16 h1 = __float2bfloat16(x);
      const float r1 = x - __bfloat162float(h1);
      const __hip_bfloat16 h2 = __float2bfloat16(r1);
      const float r2 = r1 - __bfloat162float(h2);
      const __hip_bfloat16 h3 = __float2bfloat16(r2);
      a1[e] = *(const short*)&h1;
      a2[e] = *(const short*)&h2;
      a3[e] = *(const short*)&h3;
    }
#pragma unroll
    for (int ct = 0; ct < 4; ++ct) {
      const int j = (ct0 + ct) * 16 + colL;
      const u16* wp = wsg + (size_t)j * K + k0 + kofs;
      const short8 b1 = *(const short8*)wp;
      const short8 b2 = *(const short8*)(wp + (size_t)128 * K);
      const short8 b3 = *(const short8*)(wp + (size_t)256 * K);
      acc[ct] = __builtin_amdgcn_mfma_f32_16x16x32_bf16(a1, b1, acc[ct], 0, 0, 0);
      acc[ct] = __builtin_amdgcn_mfma_f32_16x16x32_bf16(a1, b2, acc[ct], 0, 0, 0);
      acc[ct] = __builtin_amdgcn_mfma_f32_16x16x32_bf16(a2, b1, acc[ct], 0, 0, 0);
      acc[ct] = __builtin_amdgcn_mfma_f32_16x16x32_bf16(a2, b2, acc[ct], 0, 0, 0);
      acc[ct] = __builtin_amdgcn_mfma_f32_16x16x32_bf16(a1, b3, acc[ct], 0, 0, 0);
      acc[ct] = __builtin_amdgcn_mfma_f32_16x16x32_bf16(a3, b1, acc[ct], 0, 0, 0);
    }
  }

#pragma unroll
  for (int ct = 0; ct < 4; ++ct) {
    const int j = (ct0 + ct) * 16 + colL;
    const float bj = b[j];
#pragma unroll
    for (int r = 0; r < 4; ++r) {
      const int row = rbase + (lane >> 4) * 4 + r;
      if (row < M) {
        float c = acc[ct][r] + bj;
        if (mode == 1) c = fmaxf(c, 0.f);
        else if (mode == 2) c *= 2.f;
        out[(size_t)row * 128 + j] = c;
      }
    }
  }
}

__global__ __launch_bounds__(256) void k_gemm3w2(const float* A0, const u16* w0,
                                                 const float* b0, float* o0, int M0, int K0, int nb0,
                                                 const float* A1, const u16* w1,
                                                 const float* b1, float* o1, int M1, int K1,
                                                 int mode) {
  if ((int)blockIdx.x < nb0)
    gemm3w_core(A0, w0, b0, o0, M0, K0, mode, blockIdx.x, threadIdx.x);
  else
    gemm3w_core(A1, w1, b1, o1, M1, K1, mode, blockIdx.x - nb0, threadIdx.x);
}

// ---------------------------------------------------------------------------
// Merged gated fusion + copies: blocks < 5500 do fusion rows; blocks >= 5500
// do the ent/item/mm copies (128 elems per block).
// ---------------------------------------------------------------------------
__global__ void k_gatefuse2(const float* __restrict__ user_w, const float* __restrict__ mm_user,
                            const float* __restrict__ ug_w, const float* __restrict__ ug_b,
                            const float* __restrict__ item_w, const float* __restrict__ mm_item,
                            const float* __restrict__ mg_w, const float* __restrict__ mg_b,
                            float* __restrict__ emb0,
                            const float* __restrict__ ent_w,
                            float* __restrict__ outItem, float* __restrict__ outMM) {
  const int r = blockIdx.x;
  const int j = threadIdx.x;
  if (r >= N_USERS + N_ITEMS) {
    const int t = (r - (N_USERS + N_ITEMS)) * 128 + j;   // 0..383999
    if (t < N_ENT * D) emb0[(size_t)(N_USERS + N_ITEMS) * D + t] = ent_w[t];
    outItem[t] = item_w[t];
    outMM[t]   = mm_item[t];
    return;
  }
  const float* b0; const float* m0; const float* gw; const float* gb;
  if (r < N_USERS) {
    b0 = user_w + (size_t)r * D; m0 = mm_user + (size_t)r * D; gw = ug_w; gb = ug_b;
  } else {
    const int ri = r - N_USERS;
    b0 = item_w + (size_t)ri * D; m0 = mm_item + (size_t)ri * D; gw = mg_w; gb = mg_b;
  }
  float acc = 0.f;
  for (int k = 0; k < D; ++k) acc = fmaf(b0[k], gw[(size_t)k * D + j], acc);
  for (int k = 0; k < D; ++k) acc = fmaf(m0[k], gw[(size_t)(D + k) * D + j], acc);
  acc += gb[j];
  const float s1 = 1.f / (1.f + expf(-acc));
  const float g  = 1.f / (1.f + expf(-(s1 * 2.f)));
  const float bv = b0[j], mv = m0[j];
  emb0[(size_t)r * D + j] = g * bv + (1.f - g) * mv + 0.1f * bv;
}

__global__ void k_relmean(const float* __restrict__ rel, float* __restrict__ out) {
  const int j = threadIdx.x;
  float s = 0.f;
  for (int i = 0; i < 32; ++i) s += rel[i * D + j];
  out[j] = s * (1.f / 32.f);
}

// ---------------------------------------------------------------------------
// CSR build (unchanged from r13)
// ---------------------------------------------------------------------------
__global__ void k_hist(const int* __restrict__ rw, int* __restrict__ cnt) {
  const int e = blockIdx.x * 256 + threadIdx.x;
  if (e < NEDGE) atomicAdd(&cnt[rw[e]], 1);
}

__global__ __launch_bounds__(1024) void k_scan(int* __restrict__ cnt,
                                               int* __restrict__ rowptr,
                                               int* __restrict__ cursor) {
  __shared__ int part[1024];
  const int t = threadIdx.x;
  const int base = t * 8;
  int loc[8];
  int s = 0;
#pragma unroll
  for (int j = 0; j < 8; ++j) {
    const int v = (base + j < NTOT) ? cnt[base + j] : 0;
    loc[j] = s; s += v;
  }
  part[t] = s;
  __syncthreads();
  for (int off = 1; off < 1024; off <<= 1) {
    const int v = (t >= off) ? part[t - off] : 0;
    __syncthreads();
    part[t] += v;
    __syncthreads();
  }
  const int pre = (t == 0) ? 0 : part[t - 1];
#pragma unroll
  for (int j = 0; j < 8; ++j) {
    if (base + j < NTOT) {
      const int p = pre + loc[j];
      rowptr[base + j] = p;
      cursor[base + j] = p;
    }
  }
  if (t == 1023) rowptr[NTOT] = part[1023];
}

__global__ void k_scatter(const int* __restrict__ rw, int* __restrict__ cursor,
                          int* __restrict__ perm) {
  const int e = blockIdx.x * 256 + threadIdx.x;
  if (e >= NEDGE) return;
  const int pos = atomicAdd(&cursor[rw[e]], 1);
  perm[pos] = e;
}

__global__ __launch_bounds__(128) void k_spmm_csr(const float* __restrict__ dat,
                                                  const int* __restrict__ cl,
                                                  const int* __restrict__ perm,
                                                  const int* __restrict__ rowptr,
                                                  const float* __restrict__ emb,
                                                  float* __restrict__ side) {
  const int r = blockIdx.x;
  const int d = threadIdx.x;
  const int beg = rowptr[r], end = rowptr[r + 1];
  float acc = 0.f;
  for (int i = beg; i < end; ++i) {
    const int ei = perm[i];
    acc = fmaf(dat[ei], emb[(size_t)cl[ei] * D + d], acc);
  }
  side[(size_t)r * D + d] = acc;
}

// ---------------------------------------------------------------------------
// bf16-MFMA score scan + shuffle-free top selection (r12 version, PROVEN,
// byte-identical)
// ---------------------------------------------------------------------------
__global__ __launch_bounds__(256) void k_topk6v(const u16* __restrict__ qb,
                                                const u16* __restrict__ kb,
                                                int* __restrict__ cand) {
  __shared__ u64 km[4][8][97];
  const int tid  = threadIdx.x;
  const int lane = tid & 63;
  const int wave = tid >> 6;
  const int rbase = blockIdx.x * 16;
  const int sl   = blockIdx.y * 4 + wave;
  const int colL = lane & 15;
  const int g    = lane >> 4;
  const int kofs = g * 8;

  short8 aF[4];
  {
    const u16* ap = qb + (size_t)(rbase + colL) * D + kofs;
#pragma unroll
    for (int t = 0; t < 4; ++t) aF[t] = *reinterpret_cast<const short8*>(ap + t * 32);
  }

  float s[4][6]; int c[4][6];
#pragma unroll
  for (int r = 0; r < 4; ++r)
#pragma unroll
    for (int j = 0; j < 6; ++j) { s[r][j] = -3.0e38f; c[r][j] = 0x40000000 + colL * 6 + j; }

  const int tile0  = sl * 62 + (sl < 4 ? sl : 4);
  const int ntiles = 62 + (sl < 4 ? 1 : 0);
  const u16* bb = kb + (size_t)(tile0 * 16 + colL) * D + kofs;

  short8 bF[4];
#pragma unroll
  for (int t = 0; t < 4; ++t) bF[t] = *reinterpret_cast<const short8*>(bb + t * 32);

  for (int ct = 0; ct < ntiles; ++ct) {
    const int cn = (ct + 1 < ntiles) ? ct + 1 : ct;
    const u16* nb = bb + (size_t)cn * 16 * D;
    short8 bN[4];
#pragma unroll
    for (int t = 0; t < 4; ++t) bN[t] = *reinterpret_cast<const short8*>(nb + t * 32);

    f32x4 acc = {0.f, 0.f, 0.f, 0.f};
#pragma unroll
    for (int t = 0; t < 4; ++t)
      acc = __builtin_amdgcn_mfma_f32_16x16x32_bf16(aF[t], bF[t], acc, 0, 0, 0);

    const int colIdx = (tile0 + ct) * 16 + colL;
#pragma unroll
    for (int r = 0; r < 4; ++r) {
      float ks = acc[r]; int kc = colIdx;
      if (ks > s[r][5]) {
#pragma unroll
        for (int i = 0; i < 6; ++i) {
          const bool bgt = ks > s[r][i];
          const float os = s[r][i]; const int oc = c[r][i];
          s[r][i] = bgt ? ks : os;  c[r][i] = bgt ? kc : oc;
          ks      = bgt ? os : ks;  kc      = bgt ? oc : kc;
        }
      }
    }

#pragma unroll
    for (int t = 0; t < 4; ++t) bF[t] = bN[t];
  }

  u64 kk[4][6];
#pragma unroll
  for (int r = 0; r < 4; ++r)
#pragma unroll
    for (int j = 0; j < 6; ++j) {
      const u32 b = __builtin_bit_cast(u32, s[r][j]);
      const u32 mono = b ^ ((u32)(((int)b) >> 31) | 0x80000000u);
      kk[r][j] = ((u64)mono << 32) | (u64)(0xFFFFFFFFu - (u32)c[r][j]);
    }

  if (g < 2) {
#pragma unroll
    for (int r = 0; r < 4; ++r)
#pragma unroll
      for (int j = 0; j < 6; ++j)
        km[wave][4 * g + r][colL * 6 + j] = kk[r][j];
  }
  __syncthreads();
  if (g < 2) {
#pragma unroll
    for (int r = 0; r < 4; ++r) {
      int cnt[6] = {0, 0, 0, 0, 0, 0};
      for (int q2 = 0; q2 < 96; ++q2) {
        const u64 o = km[wave][4 * g + r][q2];
#pragma unroll
        for (int j = 0; j < 6; ++j) cnt[j] += (o > kk[r][j]) ? 1 : 0;
      }
      const int row = rbase + 4 * g + r;
#pragma unroll
      for (int j = 0; j < 6; ++j)
        if (cnt[j] < 16)
          cand[(size_t)row * 128 + sl * 16 + cnt[j]] = c[r][j];
    }
  }
  __syncthreads();
  if (g >= 2) {
#pragma unroll
    for (int r = 0; r < 4; ++r)
#pragma unroll
      for (int j = 0; j < 6; ++j)
        km[wave][4 * (g - 2) + r][colL * 6 + j] = kk[r][j];
  }
  __syncthreads();
  if (g >= 2) {
#pragma unroll
    for (int r = 0; r < 4; ++r) {
      int cnt[6] = {0, 0, 0, 0, 0, 0};
      for (int q2 = 0; q2 < 96; ++q2) {
        const u64 o = km[wave][4 * (g - 2) + r][q2];
#pragma unroll
        for (int j = 0; j < 6; ++j) cnt[j] += (o > kk[r][j]) ? 1 : 0;
      }
      const int row = rbase + 4 * g + r;
#pragma unroll
      for (int j = 0; j < 6; ++j)
        if (cnt[j] < 16)
          cand[(size_t)row * 128 + sl * 16 + cnt[j]] = c[r][j];
    }
  }
}

// ---------------------------------------------------------------------------
// Exact f32 rescore of 128 candidates (r17 version, PROVEN: LDS u64 rank)
// ---------------------------------------------------------------------------
__global__ __launch_bounds__(64) void k_rescore128(const float* __restrict__ qn,
                                                   const float* __restrict__ kn,
                                                   const float* __restrict__ vn,
                                                   const int* __restrict__ cand,
                                                   float* __restrict__ enext) {
  __shared__ u64 skey[128];
  const int row = blockIdx.x;
  const int lane = threadIdx.x;
  const int* cr = cand + (size_t)row * 128;
  const int c0 = cr[lane];
  const int c1 = cr[64 + lane];

  const float4* __restrict__ q4  = (const float4*)(qn + (size_t)row * D);
  const float4* __restrict__ k40 = (const float4*)(kn + (size_t)c0 * D);
  const float4* __restrict__ k41 = (const float4*)(kn + (size_t)c1 * D);
  float s0 = 0.f, s1 = 0.f;
#pragma unroll 8
  for (int j = 0; j < 32; ++j) {
    const float4 qv = q4[j];
    const float4 a = k40[j], b = k41[j];
    s0 = fmaf(qv.x, a.x, s0); s0 = fmaf(qv.y, a.y, s0);
    s0 = fmaf(qv.z, a.z, s0); s0 = fmaf(qv.w, a.w, s0);
    s1 = fmaf(qv.x, b.x, s1); s1 = fmaf(qv.y, b.y, s1);
    s1 = fmaf(qv.z, b.z, s1); s1 = fmaf(qv.w, b.w, s1);
  }
  const float inv = 0.088388347648318447f;   // 1/sqrt(128)
  s0 *= inv; s1 *= inv;

  const u32 b0i = __builtin_bit_cast(u32, s0);
  const u32 b1i = __builtin_bit_cast(u32, s1);
  const u64 key0 = ((u64)(b0i ^ ((u32)(((int)b0i) >> 31) | 0x80000000u)) << 32)
                   | (u64)(0xFFFFFFFFu - (u32)c0);
  const u64 key1 = ((u64)(b1i ^ ((u32)(((int)b1i) >> 31) | 0x80000000u)) << 32)
                   | (u64)(0xFFFFFFFFu - (u32)c1);
  skey[lane] = key0;
  skey[64 + lane] = key1;
  __syncthreads();

  int r0 = 0, r1 = 0;
#pragma unroll 8
  for (int j = 0; j < 128; ++j) {
    const u64 o = skey[j];
    r0 += (o > key0) ? 1 : 0;
    r1 += (o > key1) ? 1 : 0;
  }
  const bool sel0 = r0 < 16, sel1 = r1 < 16;

  float v = fmaxf(sel0 ? s0 : -3.0e38f, sel1 ? s1 : -3.0e38f);
#pragma unroll
  for (int d2 = 1; d2 < 64; d2 <<= 1) v = fmaxf(v, __shfl_xor(v, d2));
  const float e0 = sel0 ? expf(s0 - v) : 0.f;
  const float e1 = sel1 ? expf(s1 - v) : 0.f;
  float Z = e0 + e1;
#pragma unroll
  for (int d2 = 1; d2 < 64; d2 <<= 1) Z += __shfl_xor(Z, d2);
  const float w0 = e0 / Z, w1 = e1 / Z;

  float a0 = 0.f, a1 = 0.f;
  unsigned long long bm0 = __ballot(sel0);
  while (bm0) {
    const int src = __ffsll(bm0) - 1; bm0 &= bm0 - 1;
    const float wj = __shfl(w0, src);
    const int   cj = __shfl(c0, src);
    const float* __restrict__ vr = vn + (size_t)cj * D;
    a0 = fmaf(wj, vr[lane], a0);
    a1 = fmaf(wj, vr[64 + lane], a1);
  }
  unsigned long long bm1 = __ballot(sel1);
  while (bm1) {
    const int src = __ffsll(bm1) - 1; bm1 &= bm1 - 1;
    const float wj = __shfl(w1, src);
    const int   cj = __shfl(c1, src);
    const float* __restrict__ vr = vn + (size_t)cj * D;
    a0 = fmaf(wj, vr[lane], a0);
    a1 = fmaf(wj, vr[64 + lane], a1);
  }
  enext[(size_t)row * D + lane]      = fmaxf(a0, 0.f);
  enext[(size_t)row * D + 64 + lane] = fmaxf(a1, 0.f);
}

// ---------------------------------------------------------------------------
// final = [e0|e1|e2] @ la_w + la_b, row-L2-normalized (unchanged)
// ---------------------------------------------------------------------------
__global__ void k_final_norm(const float* __restrict__ e0, const float* __restrict__ e1,
                             const float* __restrict__ e2, const float* __restrict__ law,
                             const float* __restrict__ lab, float* __restrict__ out) {
  __shared__ float red[128];
  const int r = blockIdx.x;
  const int j = threadIdx.x;
  const float* __restrict__ a0 = e0 + (size_t)r * D;
  const float* __restrict__ a1 = e1 + (size_t)r * D;
  const float* __restrict__ a2 = e2 + (size_t)r * D;
  float acc = lab[j];
  for (int k = 0; k < D; ++k) acc = fmaf(a0[k], law[(size_t)k * D + j], acc);
  for (int k = 0; k < D; ++k) acc = fmaf(a1[k], law[(size_t)(D + k) * D + j], acc);
  for (int k = 0; k < D; ++k) acc = fmaf(a2[k], law[(size_t)(2 * D + k) * D + j], acc);
  red[j] = acc * acc;
  __syncthreads();
  for (int st = 64; st > 0; st >>= 1) {
    if (j < st) red[j] += red[j + st];
    __syncthreads();
  }
  const float nrm = fmaxf(sqrtf(red[0]), 1e-12f);
  const float o = acc / nrm;
  if (r < N_USERS) out[(size_t)r * D + j] = o;
  else             out[(size_t)N_USERS * D + (size_t)(r - N_USERS) * D + j] = o;
}

// ---------------------------------------------------------------------------
extern "C" void kernel_launch(void* const* d_in, const int* in_sizes, int n_in,
                              void* d_out, int out_size, void* d_ws, size_t ws_size,
                              hipStream_t stream) {
  const float* user_w = (const float*)d_in[0];
  const float* item_w = (const float*)d_in[1];
  const float* ent_w  = (const float*)d_in[2];
  const float* rel_w  = (const float*)d_in[3];
  const float* mfeat  = (const float*)d_in[4];
  const float* ufeat  = (const float*)d_in[5];
  const float* me_w1  = (const float*)d_in[6];
  const float* me_b1  = (const float*)d_in[7];
  const float* me_w2  = (const float*)d_in[8];
  const float* me_b2  = (const float*)d_in[9];
  const float* ue_w1  = (const float*)d_in[10];
  const float* ue_b1  = (const float*)d_in[11];
  const float* ue_w2  = (const float*)d_in[12];
  const float* ue_b2  = (const float*)d_in[13];
  const float* cm_vw  = (const float*)d_in[18];
  const float* cm_vb  = (const float*)d_in[19];
  const float* cm_ow  = (const float*)d_in[20];
  const float* cm_ob  = (const float*)d_in[21];
  const float* mg_w   = (const float*)d_in[22];
  const float* mg_b   = (const float*)d_in[23];
  const float* ug_w   = (const float*)d_in[24];
  const float* ug_b   = (const float*)d_in[25];
  const float* gnn_qw = (const float*)d_in[26];
  const float* gnn_qb = (const float*)d_in[27];
  const float* gnn_kw = (const float*)d_in[28];
  const float* gnn_kb = (const float*)d_in[29];
  const float* gnn_vw = (const float*)d_in[30];
  const float* gnn_vb = (const float*)d_in[31];
  const float* la_w   = (const float*)d_in[32];
  const float* la_b   = (const float*)d_in[33];
  const float* adj_d  = (const float*)d_in[34];
  const int*   adj_r  = (const int*)d_in[35];
  const int*   adj_c  = (const int*)d_in[36];
  float* out = (float*)d_out;
  float* ws  = (float*)d_ws;

  // ---- workspace layout (floats) ----
  size_t off = 0;
  float* mm_item = ws + off; off += (size_t)N_ITEMS * D;
  float* mm_user = ws + off; off += (size_t)N_USERS * D;
  float* enc     = ws + off; off += (size_t)N_ITEMS * D;
  float* tmp     = ws + off; off += (size_t)N_ITEMS * D;
  float* emb0    = ws + off; off += (size_t)NTOT * D;
  float* emb1    = ws + off; off += (size_t)NTOT * D;
  float* emb2    = ws + off; off += (size_t)NTOT * D;
  float* side    = ws + off; off += (size_t)NTOT * D;
  float* qn      = ws + off; off += (size_t)NTOT * D;
  float* kn      = ws + off; off += (size_t)NTOT * D;
  float* vn      = ws + off; off += (size_t)NTOT * D;
  float* relmean = ws + off; off += D;
  u16* arena = (u16*)(ws + off); off += 491520;
  u16* qb = (u16*)mm_user;
  u16* kb = qb + (size_t)NTOT * D;
  int* cand = (int*)side;
  int* rowptr = (int*)emb2;
  int* cursor = rowptr + 8064;
  int* permB  = cursor + 8064;
  float* utmp = side;   // user hidden layer (dead until first spmm)

  // order: me_w1, me_w2, ue_w1, ue_w2, cm_vw, cm_ow, qw0, kw0, vw0, qw1, kw1, vw1
  static const int Ks[NMAT]  = {768, 128, 512, 128, 128, 128, 128, 128, 128, 128, 128, 128};
  int ofs[NMAT], cum[NMAT + 1];
  {
    int o = 0, cc = 0;
    for (int i = 0; i < NMAT; ++i) {
      ofs[i] = o; o += 3 * Ks[i] * 128;
      cum[i] = cc; cc += Ks[i] * 128;
    }
    cum[NMAT] = cc;
  }

  WsplitArgs wa;
  const float* wptr[NMAT] = {me_w1, me_w2, ue_w1, ue_w2, cm_vw, cm_ow,
                             gnn_qw, gnn_kw, gnn_vw,
                             gnn_qw + (size_t)D * D, gnn_kw + (size_t)D * D,
                             gnn_vw + (size_t)D * D};
  for (int i = 0; i < NMAT; ++i) {
    wa.w[i] = wptr[i];
    wa.useks[i] = (i == 7 || i == 10) ? 1 : 0;
    wa.K[i] = Ks[i];
    wa.cum[i] = cum[i];
    wa.ofs[i] = ofs[i];
  }
  wa.cum[NMAT] = cum[NMAT];

  k_relmean<<<1, D, 0, stream>>>(rel_w, relmean);
  k_wsplit_all<<<(cum[NMAT] + 255) / 256, 256, 0, stream>>>(wa, relmean, arena);

  // ---- modality encoders: batched item+user chains ----
  const int nbI1 = (3000 + 31) / 32;   // 94
  const int nbU1 = (2500 + 31) / 32;   // 79
  k_gemm3w2<<<nbI1 + nbU1, 256, 0, stream>>>(
      mfeat, arena + ofs[0], me_b1, tmp,  3000, 768, nbI1,
      ufeat, arena + ofs[2], ue_b1, utmp, 2500, 512, 1);
  const int nbI2 = (3000 + 63) / 64;   // 47
  const int nbU2 = (2500 + 63) / 64;   // 40
  k_gemm3b<<<nbI2 + nbU2, 256, 0, stream>>>(
      tmp,  arena + ofs[1], me_b2, enc,     3000, 128, nbI2,
      utmp, arena + ofs[3], ue_b2, mm_user, 2500, 128, 1);
  // ---- collapsed cross-modal attention: mm_item = 2*((enc@vw+vb)@ow+ob) ----
  k_gemm3<<<(3000 + 63) / 64, 256, 0, stream>>>(enc, arena + ofs[4], cm_vb, tmp, nullptr, 3000, 128, 0);
  k_gemm3<<<(3000 + 63) / 64, 256, 0, stream>>>(tmp, arena + ofs[5], cm_ob, mm_item, nullptr, 3000, 128, 2);
  // ---- gated fusion + copies (one launch) -> emb0 / out ----
  k_gatefuse2<<<N_USERS + N_ITEMS + 3000, D, 0, stream>>>(
      user_w, mm_user, ug_w, ug_b, item_w, mm_item, mg_w, mg_b, emb0,
      ent_w,
      out + (size_t)(N_USERS + N_ITEMS) * D,
      out + (size_t)(N_USERS + 2 * N_ITEMS) * D);

  // ---- CSR build ----
  hipMemsetAsync(cursor, 0, NTOT * sizeof(int), stream);
  k_hist<<<(NEDGE + 255) / 256, 256, 0, stream>>>(adj_r, cursor);
  k_scan<<<1, 1024, 0, stream>>>(cursor, rowptr, cursor);
  k_scatter<<<(NEDGE + 255) / 256, 256, 0, stream>>>(adj_r, cursor, permB);

  // ---- GNN layers ----
  const float* eml[3] = {emb0, emb1, emb2};
  for (int l = 0; l < 2; ++l) {
    const float* e = eml[l];
    float* enext   = (float*)eml[l + 1];
    k_spmm_csr<<<NTOT, 128, 0, stream>>>(adj_d, adj_c, permB, rowptr, e, side);
    const int nbq = (NTOT + 63) / 64;   // 125
    k_gemm3qkv<<<2 * nbq, 256, 0, stream>>>(
        e, arena + ofs[6 + 3 * l], gnn_qb + (size_t)l * D, qn, qb,
        side, arena + ofs[7 + 3 * l], gnn_kb + (size_t)l * D, kn, kb,
        arena + ofs[8 + 3 * l], gnn_vb + (size_t)l * D, vn,
        NTOT, nbq);
    dim3 tkgrid(NTOT / 16, 2);
    k_topk6v<<<tkgrid, 256, 0, stream>>>(qb, kb, cand);
    k_rescore128<<<NTOT, 64, 0, stream>>>(qn, kn, vn, cand, enext);
  }

  // ---- layer aggregation + normalize -> d_out ----
  k_final_norm<<<N_USERS + N_ITEMS, D, 0, stream>>>(emb0, emb1, emb2, la_w, la_b, out);
}